// Round 1
// baseline (4588.405 us; speedup 1.0000x reference)
//
#include <hip/hip_runtime.h>
#include <math.h>

namespace {

constexpr int B  = 8;
constexpr int C  = 192;   // Cin == Cout == 192
constexpr int H  = 96;
constexpr int W  = 96;
constexpr int FK = 9;     // 3x3

// ---------------------------------------------------------------------------
// conv3x3, stride 1, pad 1, static weights w[O][I][3][3].
// Block: 256 thr = 16x16 spatial tile, 16 output channels per block.
// grid: (36 spatial tiles, 12 co-tiles, 8 batch)
// ---------------------------------------------------------------------------
__global__ __launch_bounds__(256) void conv3x3_w(const float* __restrict__ x,
                                                 const float* __restrict__ w,
                                                 float* __restrict__ y) {
    __shared__ float xs[18][19];
    __shared__ float ws[16][12];   // 9 taps + pad to 12 (float4-readable)
    const int tid   = threadIdx.x;
    const int tx    = tid & 15, ty = tid >> 4;
    const int tileY = (blockIdx.x / 6) * 16, tileX = (blockIdx.x % 6) * 16;
    const int co0   = blockIdx.y * 16;
    const int b     = blockIdx.z;

    float acc[16];
#pragma unroll
    for (int j = 0; j < 16; ++j) acc[j] = 0.f;

    for (int ci = 0; ci < C; ++ci) {
        __syncthreads();
        // stage 18x18 input tile (zero-padded at borders)
        for (int e = tid; e < 324; e += 256) {
            const int i  = e / 18, j = e - i * 18;
            const int gy = tileY + i - 1, gx = tileX + j - 1;
            float v = 0.f;
            if (gy >= 0 && gy < H && gx >= 0 && gx < W)
                v = x[(((size_t)b * C + ci) * H + gy) * W + gx];
            xs[i][j] = v;
        }
        // stage 16 co x 9 taps (padded rows of 12)
        if (tid < 192) {
            const int j = tid / 12, pp = tid - j * 12;
            ws[j][pp] = (pp < 9) ? w[((size_t)(co0 + j) * C + ci) * 9 + pp] : 0.f;
        }
        __syncthreads();

        float xr[9];
#pragma unroll
        for (int p = 0; p < 9; ++p) xr[p] = xs[ty + p / 3][tx + p % 3];
#pragma unroll
        for (int j = 0; j < 16; ++j) {
            const float4* wr = reinterpret_cast<const float4*>(&ws[j][0]);
            const float4 w0 = wr[0], w1 = wr[1], w2 = wr[2];
            float a = acc[j];
            a = fmaf(w0.x, xr[0], a); a = fmaf(w0.y, xr[1], a); a = fmaf(w0.z, xr[2], a);
            a = fmaf(w0.w, xr[3], a); a = fmaf(w1.x, xr[4], a); a = fmaf(w1.y, xr[5], a);
            a = fmaf(w1.z, xr[6], a); a = fmaf(w1.w, xr[7], a); a = fmaf(w2.x, xr[8], a);
            acc[j] = a;
        }
    }
    const int oy = tileY + ty, ox = tileX + tx;
#pragma unroll
    for (int j = 0; j < 16; ++j)
        y[(((size_t)b * C + co0 + j) * H + oy) * W + ox] = acc[j];
}

// ---------------------------------------------------------------------------
// attn[b,p,c,o] = sum_l kconv[b,c,3*lh+ph,3*lw+pw] * qconv[b,o,3*lh+ph,3*lw+pw]
// Per (b,p): 192x1024x192 GEMM. Block computes a 32x32 (c,o) tile.
// grid: (36 = 6 ctiles x 6 otiles, 9 taps, 8 batch)
// ---------------------------------------------------------------------------
__global__ __launch_bounds__(256) void attn_k(const float* __restrict__ kc,
                                              const float* __restrict__ qc,
                                              float* __restrict__ attn) {
    __shared__ float Ks[32][33];
    __shared__ float Qs[32][33];
    const int tid = threadIdx.x;
    const int ct  = (blockIdx.x / 6) * 32, ot = (blockIdx.x % 6) * 32;
    const int p   = blockIdx.y, ph = p / 3, pw = p % 3;
    const int b   = blockIdx.z;
    const int tx  = tid & 15, ty = tid >> 4;
    const int ri  = tid >> 3, rm = (tid & 7) * 4;

    float acc00 = 0.f, acc01 = 0.f, acc10 = 0.f, acc11 = 0.f;

    for (int lc = 0; lc < 32; ++lc) {
        const int row = 3 * lc + ph;
        __syncthreads();
#pragma unroll
        for (int q = 0; q < 4; ++q) {
            const int m = rm + q;
            Ks[ri][m] = kc[(((size_t)b * C + ct + ri) * H + row) * W + 3 * m + pw];
            Qs[m][ri] = qc[(((size_t)b * C + ot + ri) * H + row) * W + 3 * m + pw];
        }
        __syncthreads();
#pragma unroll
        for (int m = 0; m < 32; ++m) {
            const float k0 = Ks[2 * ty][m], k1 = Ks[2 * ty + 1][m];
            const float q0 = Qs[m][2 * tx], q1 = Qs[m][2 * tx + 1];
            acc00 = fmaf(k0, q0, acc00); acc01 = fmaf(k0, q1, acc01);
            acc10 = fmaf(k1, q0, acc10); acc11 = fmaf(k1, q1, acc11);
        }
    }
    float* ap = attn + (((size_t)b * FK + p) * C) * C;
    ap[(ct + 2 * ty) * C + ot + 2 * tx]         = acc00;
    ap[(ct + 2 * ty) * C + ot + 2 * tx + 1]     = acc01;
    ap[(ct + 2 * ty + 1) * C + ot + 2 * tx]     = acc10;
    ap[(ct + 2 * ty + 1) * C + ot + 2 * tx + 1] = acc11;
}

// ---------------------------------------------------------------------------
// global sum / sum-of-squares over attn (2,654,208 floats), double precision
// ---------------------------------------------------------------------------
__global__ __launch_bounds__(256) void reduce_k(const float* __restrict__ a,
                                                double* __restrict__ part) {
    const int n = B * FK * C * C;
    double s = 0.0, ss = 0.0;
    for (int i = blockIdx.x * 256 + threadIdx.x; i < n; i += 1024 * 256) {
        const double v = (double)a[i];
        s += v; ss += v * v;
    }
    __shared__ double ls[256], lss[256];
    ls[threadIdx.x] = s; lss[threadIdx.x] = ss;
    __syncthreads();
    for (int st = 128; st; st >>= 1) {
        if (threadIdx.x < st) {
            ls[threadIdx.x]  += ls[threadIdx.x + st];
            lss[threadIdx.x] += lss[threadIdx.x + st];
        }
        __syncthreads();
    }
    if (threadIdx.x == 0) {
        part[2 * blockIdx.x]     = ls[0];
        part[2 * blockIdx.x + 1] = lss[0];
    }
}

__global__ __launch_bounds__(256) void finalize_k(const double* __restrict__ part,
                                                  const float* __restrict__ momp,
                                                  float* __restrict__ scal) {
    __shared__ double ls[256], lss[256];
    double s = 0.0, ss = 0.0;
    for (int i = threadIdx.x; i < 1024; i += 256) {
        s += part[2 * i]; ss += part[2 * i + 1];
    }
    ls[threadIdx.x] = s; lss[threadIdx.x] = ss;
    __syncthreads();
    for (int st = 128; st; st >>= 1) {
        if (threadIdx.x < st) {
            ls[threadIdx.x]  += ls[threadIdx.x + st];
            lss[threadIdx.x] += lss[threadIdx.x + st];
        }
        __syncthreads();
    }
    if (threadIdx.x == 0) {
        const double n    = (double)(B * FK * C * C);
        const double mean = ls[0] / n;
        double var        = (lss[0] - ls[0] * ls[0] / n) / (n - 1.0);
        if (var < 0.0) var = 0.0;
        const double sd    = sqrt(var);
        const double scale = 1.0 / (sd + 1e-4);
        const double mom   = (double)momp[0];
        scal[0] = (float)(mom + scale);   // alpha:  w = alpha*a + beta
        scal[1] = (float)(-mean * scale); // beta
    }
}

// ---------------------------------------------------------------------------
// final conv: out[b,o,y,x] = sum_{c,p} (alpha*attn[b,p,c,o]+beta) * x1pad[...]
// same structure as conv3x3_w, weights from normalized attn (per-batch)
// ---------------------------------------------------------------------------
__global__ __launch_bounds__(256) void conv_attn(const float* __restrict__ x,
                                                 const float* __restrict__ attn,
                                                 const float* __restrict__ scal,
                                                 float* __restrict__ y) {
    __shared__ float xs[18][19];
    __shared__ float ws[16][12];
    const int tid   = threadIdx.x;
    const int tx    = tid & 15, ty = tid >> 4;
    const int tileY = (blockIdx.x / 6) * 16, tileX = (blockIdx.x % 6) * 16;
    const int co0   = blockIdx.y * 16;
    const int b     = blockIdx.z;
    const float alpha = scal[0], beta = scal[1];

    float acc[16];
#pragma unroll
    for (int j = 0; j < 16; ++j) acc[j] = 0.f;

    for (int ci = 0; ci < C; ++ci) {
        __syncthreads();
        for (int e = tid; e < 324; e += 256) {
            const int i  = e / 18, j = e - i * 18;
            const int gy = tileY + i - 1, gx = tileX + j - 1;
            float v = 0.f;
            if (gy >= 0 && gy < H && gx >= 0 && gx < W)
                v = x[(((size_t)b * C + ci) * H + gy) * W + gx];
            xs[i][j] = v;
        }
        if (tid < 192) {
            const int j = tid / 12, pp = tid - j * 12;
            float v = 0.f;
            if (pp < 9)
                v = fmaf(alpha, attn[(((size_t)b * FK + pp) * C + ci) * C + co0 + j], beta);
            ws[j][pp] = v;
        }
        __syncthreads();

        float xr[9];
#pragma unroll
        for (int p = 0; p < 9; ++p) xr[p] = xs[ty + p / 3][tx + p % 3];
#pragma unroll
        for (int j = 0; j < 16; ++j) {
            const float4* wr = reinterpret_cast<const float4*>(&ws[j][0]);
            const float4 w0 = wr[0], w1 = wr[1], w2 = wr[2];
            float a = acc[j];
            a = fmaf(w0.x, xr[0], a); a = fmaf(w0.y, xr[1], a); a = fmaf(w0.z, xr[2], a);
            a = fmaf(w0.w, xr[3], a); a = fmaf(w1.x, xr[4], a); a = fmaf(w1.y, xr[5], a);
            a = fmaf(w1.z, xr[6], a); a = fmaf(w1.w, xr[7], a); a = fmaf(w2.x, xr[8], a);
            acc[j] = a;
        }
    }
    const int oy = tileY + ty, ox = tileX + tx;
#pragma unroll
    for (int j = 0; j < 16; ++j)
        y[(((size_t)b * C + co0 + j) * H + oy) * W + ox] = acc[j];
}

} // anonymous namespace

extern "C" void kernel_launch(void* const* d_in, const int* in_sizes, int n_in,
                              void* d_out, int out_size, void* d_ws, size_t ws_size,
                              hipStream_t stream) {
    (void)in_sizes; (void)n_in; (void)out_size; (void)ws_size;
    const float* x1   = (const float*)d_in[0];
    const float* x2   = (const float*)d_in[1];
    const float* kw   = (const float*)d_in[2];
    const float* qw   = (const float*)d_in[3];
    const float* momp = (const float*)d_in[4];
    float* out = (float*)d_out;

    char* ws = (char*)d_ws;
    float*  kconv = (float*)ws;                                   // 56,623,104 B
    float*  attn  = (float*)(ws + 56623104);                      // 10,616,832 B
    double* part  = (double*)(ws + 56623104 + 10616832);          //     16,384 B
    float*  scal  = (float*)(ws + 56623104 + 10616832 + 16384);   //          8 B
    float*  qconv = out;  // d_out is exactly B*C*H*W floats; reused as scratch,
                          // fully overwritten by conv_attn at the end.

    dim3 cgrid(36, 12, 8);
    conv3x3_w<<<cgrid, 256, 0, stream>>>(x1, kw, kconv);
    conv3x3_w<<<cgrid, 256, 0, stream>>>(x2, qw, qconv);

    dim3 agrid(36, 9, 8);
    attn_k<<<agrid, 256, 0, stream>>>(kconv, qconv, attn);

    reduce_k<<<1024, 256, 0, stream>>>(attn, part);
    finalize_k<<<1, 256, 0, stream>>>(part, momp, scal);

    conv_attn<<<cgrid, 256, 0, stream>>>(x1, attn, scal, out);
}

// Round 2
// 834.932 us; speedup vs baseline: 5.4955x; 5.4955x over previous
//
#include <hip/hip_runtime.h>
#include <math.h>

typedef __attribute__((ext_vector_type(8))) short s16x8;
typedef __attribute__((ext_vector_type(4))) float f32x4;

namespace {

constexpr int B  = 8;
constexpr int C  = 192;
constexpr int H  = 96;
constexpr int W  = 96;
constexpr int FK = 9;
constexpr int HP = 98;   // padded

__device__ inline unsigned short f2b(float f) {
    unsigned int x = __float_as_uint(f);
    x += 0x7fffu + ((x >> 16) & 1u);
    return (unsigned short)(x >> 16);
}
__device__ inline float b2f(unsigned short u) {
    return __uint_as_float(((unsigned int)u) << 16);
}

// ---------------------------------------------------------------------------
// x[b][c][96][96] f32  ->  xpadT[b][98][98][192] bf16 (channel-last, borders
// pre-zeroed by memset). LDS transpose for coalescing both sides.
// grid (3 xtiles, 96 y, 8 b), 256 thr
// ---------------------------------------------------------------------------
__global__ __launch_bounds__(256) void prep_x(const float* __restrict__ x,
                                              unsigned short* __restrict__ xpadT) {
    __shared__ float xs[192][33];
    const int tid = threadIdx.x;
    const int x0  = blockIdx.x * 32;
    const int y   = blockIdx.y;
    const int b   = blockIdx.z;
    for (int e = tid; e < 192 * 32; e += 256) {
        const int ci = e >> 5, xx = e & 31;
        xs[ci][xx] = x[(((size_t)b * C + ci) * H + y) * W + x0 + xx];
    }
    __syncthreads();
    for (int e = tid; e < 32 * 192; e += 256) {
        const int pos = e / 192, ci = e - pos * 192;
        xpadT[(((size_t)(b * HP + y + 1)) * HP + x0 + pos + 1) * 192 + ci] = f2b(xs[ci][pos]);
    }
}

// ---------------------------------------------------------------------------
// w[co][ci][p] f32 -> wA[p][co][ci] bf16, both weight tensors in one launch
// grid 2592, 256 thr (2 * 331776 elems)
// ---------------------------------------------------------------------------
__global__ __launch_bounds__(256) void prep_w(const float* __restrict__ kw,
                                              const float* __restrict__ qw,
                                              unsigned short* __restrict__ kwA,
                                              unsigned short* __restrict__ qwA) {
    int idx = blockIdx.x * 256 + threadIdx.x;
    const int n = FK * C * C;
    const float* src = kw;
    unsigned short* dst = kwA;
    if (idx >= n) { idx -= n; src = qw; dst = qwA; }
    const int p = idx / (C * C), r = idx - p * C * C;
    const int co = r / C, ci = r - co * C;
    dst[idx] = f2b(src[((size_t)co * C + ci) * FK + p]);
}

// ---------------------------------------------------------------------------
// MFMA implicit-GEMM conv3x3.
// MODE 0: weights = wA[p][co][ci] bf16 (global->reg A frags), out bf16 NCHW.
// MODE 1: weights = alpha*attnT[b][p][co][ci]+beta (f32->bf16 in reg), out f32.
// Block: 6 waves = 3 co-strips(64) x 2 s-halves(48); tile = 192 co x 96 s
// (one output row y). B = whole padded input row staged in LDS per dy,
// XOR-swizzled; A frags straight from global (L2-hot).
// grid (96 y, 8 b), 384 thr
// ---------------------------------------------------------------------------
template <int MODE>
__global__ __launch_bounds__(384)
void conv_mfma(const unsigned short* __restrict__ xpadT,
               const unsigned short* __restrict__ wA,
               const float* __restrict__ attnT,
               const float* __restrict__ scal,
               void* __restrict__ yout) {
    __shared__ __align__(16) char smem[HP * 384];   // 98 pos x 192 ci bf16
    const int tid  = threadIdx.x;
    const int y    = blockIdx.x;
    const int b    = blockIdx.y;
    const int lane = tid & 63, wid = tid >> 6;
    const int wco  = wid >> 1;          // 0..2 : co strip of 64
    const int wsx  = wid & 1;           // 0..1 : s half of 48
    const int ln15 = lane & 15, kg = lane >> 4;

    float alpha = 0.f, beta = 0.f;
    if (MODE == 1) { alpha = scal[0]; beta = scal[1]; }

    // B fragment address pieces: pos = wsx*48 + j*16 + ln15 + dx
    int bbase[3][3], bsw[3][3];
#pragma unroll
    for (int j = 0; j < 3; ++j)
#pragma unroll
        for (int dx = 0; dx < 3; ++dx) {
            const int pos   = wsx * 48 + j * 16 + ln15 + dx;
            bbase[j][dx] = pos * 384;
            bsw[j][dx]   = (pos & 7) << 4;
        }

    f32x4 acc[4][3];
#pragma unroll
    for (int i = 0; i < 4; ++i)
#pragma unroll
        for (int j = 0; j < 3; ++j)
            acc[i][j] = (f32x4){0.f, 0.f, 0.f, 0.f};

    for (int dy = 0; dy < 3; ++dy) {
        const int ypad = y + dy;
        __syncthreads();
        // stage full padded row: 98 pos x 24 chunks(16B) = 2352 chunks
        for (int c = tid; c < HP * 24; c += 384) {
            const int pos = c / 24, c16 = c - pos * 24;
            const unsigned short* gp =
                xpadT + (((size_t)(b * HP + ypad)) * HP + pos) * 192 + c16 * 8;
            const int off = pos * 384 + ((c16 * 16) ^ ((pos & 7) << 4));
            *(s16x8*)(smem + off) = *(const s16x8*)gp;
        }
        __syncthreads();

        for (int cc = 0; cc < 6; ++cc) {
#pragma unroll
            for (int dx = 0; dx < 3; ++dx) {
                const int p = 3 * dy + dx;
                s16x8 af[4];
                if (MODE == 0) {
#pragma unroll
                    for (int i = 0; i < 4; ++i) {
                        const int row = wco * 64 + i * 16 + ln15;
                        af[i] = *(const s16x8*)(wA + ((size_t)p * C + row) * C + cc * 32 + kg * 8);
                    }
                } else {
#pragma unroll
                    for (int i = 0; i < 4; ++i) {
                        const int row = wco * 64 + i * 16 + ln15;
                        const float* gp =
                            attnT + (((size_t)(b * FK + p)) * C + row) * C + cc * 32 + kg * 8;
                        const float4 f0 = ((const float4*)gp)[0];
                        const float4 f1 = ((const float4*)gp)[1];
                        s16x8 v;
                        v[0] = (short)f2b(fmaf(alpha, f0.x, beta));
                        v[1] = (short)f2b(fmaf(alpha, f0.y, beta));
                        v[2] = (short)f2b(fmaf(alpha, f0.z, beta));
                        v[3] = (short)f2b(fmaf(alpha, f0.w, beta));
                        v[4] = (short)f2b(fmaf(alpha, f1.x, beta));
                        v[5] = (short)f2b(fmaf(alpha, f1.y, beta));
                        v[6] = (short)f2b(fmaf(alpha, f1.z, beta));
                        v[7] = (short)f2b(fmaf(alpha, f1.w, beta));
                        af[i] = v;
                    }
                }
                s16x8 bv[3];
#pragma unroll
                for (int j = 0; j < 3; ++j)
                    bv[j] = *(const s16x8*)(smem + bbase[j][dx] +
                                            (((cc * 64 + kg * 16)) ^ bsw[j][dx]));
#pragma unroll
                for (int i = 0; i < 4; ++i)
#pragma unroll
                    for (int j = 0; j < 3; ++j)
                        acc[i][j] = __builtin_amdgcn_mfma_f32_16x16x32_bf16(
                            af[i], bv[j], acc[i][j], 0, 0, 0);
            }
        }
    }

    // epilogue: D col = lane&15 (s), row = kg*4+reg (co within 16)
    if (MODE == 0) {
        unsigned short* yb = (unsigned short*)yout;
#pragma unroll
        for (int i = 0; i < 4; ++i)
#pragma unroll
            for (int r = 0; r < 4; ++r) {
                const int co = wco * 64 + i * 16 + kg * 4 + r;
                const size_t base = (((size_t)b * C + co) * H + y) * W;
#pragma unroll
                for (int j = 0; j < 3; ++j)
                    yb[base + wsx * 48 + j * 16 + ln15] = f2b(acc[i][j][r]);
            }
    } else {
        float* yf = (float*)yout;
#pragma unroll
        for (int i = 0; i < 4; ++i)
#pragma unroll
            for (int r = 0; r < 4; ++r) {
                const int co = wco * 64 + i * 16 + kg * 4 + r;
                const size_t base = (((size_t)b * C + co) * H + y) * W;
#pragma unroll
                for (int j = 0; j < 3; ++j)
                    yf[base + wsx * 48 + j * 16 + ln15] = acc[i][j][r];
            }
    }
}

// ---------------------------------------------------------------------------
// attn[b,p,c,o] = sum_l kc[b,c,3lh+ph,3lw+pw] * qc[b,o,...]; bf16 in, f32 out,
// written TRANSPOSED: attnT[b][p][o][c].
// grid (36, 9, 8), 256 thr
// ---------------------------------------------------------------------------
__global__ __launch_bounds__(256) void attn_k(const unsigned short* __restrict__ kc,
                                              const unsigned short* __restrict__ qc,
                                              float* __restrict__ attnT) {
    __shared__ float Ks[32][33];
    __shared__ float Qs[32][33];
    const int tid = threadIdx.x;
    const int ct  = (blockIdx.x / 6) * 32, ot = (blockIdx.x % 6) * 32;
    const int p   = blockIdx.y, ph = p / 3, pw = p % 3;
    const int b   = blockIdx.z;
    const int tx  = tid & 15, ty = tid >> 4;
    const int ri  = tid >> 3, rm = (tid & 7) * 4;

    float acc00 = 0.f, acc01 = 0.f, acc10 = 0.f, acc11 = 0.f;

    for (int lc = 0; lc < 32; ++lc) {
        const int row = 3 * lc + ph;
        __syncthreads();
#pragma unroll
        for (int q = 0; q < 4; ++q) {
            const int m = rm + q;
            Ks[ri][m] = b2f(kc[(((size_t)b * C + ct + ri) * H + row) * W + 3 * m + pw]);
            Qs[m][ri] = b2f(qc[(((size_t)b * C + ot + ri) * H + row) * W + 3 * m + pw]);
        }
        __syncthreads();
#pragma unroll
        for (int m = 0; m < 32; ++m) {
            const float k0 = Ks[2 * ty][m], k1 = Ks[2 * ty + 1][m];
            const float q0 = Qs[m][2 * tx], q1 = Qs[m][2 * tx + 1];
            acc00 = fmaf(k0, q0, acc00); acc01 = fmaf(k0, q1, acc01);
            acc10 = fmaf(k1, q0, acc10); acc11 = fmaf(k1, q1, acc11);
        }
    }
    float* ap = attnT + ((size_t)(b * FK + p)) * C * C;
    ap[(ot + 2 * tx) * C + ct + 2 * ty]         = acc00;
    ap[(ot + 2 * tx + 1) * C + ct + 2 * ty]     = acc01;
    ap[(ot + 2 * tx) * C + ct + 2 * ty + 1]     = acc10;
    ap[(ot + 2 * tx + 1) * C + ct + 2 * ty + 1] = acc11;
}

// ---------------------------------------------------------------------------
// global mean/std over attnT, double precision two-stage
// ---------------------------------------------------------------------------
__global__ __launch_bounds__(256) void reduce_k(const float* __restrict__ a,
                                                double* __restrict__ part) {
    const int n = B * FK * C * C;
    double s = 0.0, ss = 0.0;
    for (int i = blockIdx.x * 256 + threadIdx.x; i < n; i += 1024 * 256) {
        const double v = (double)a[i];
        s += v; ss += v * v;
    }
    __shared__ double ls[256], lss[256];
    ls[threadIdx.x] = s; lss[threadIdx.x] = ss;
    __syncthreads();
    for (int st = 128; st; st >>= 1) {
        if (threadIdx.x < st) {
            ls[threadIdx.x]  += ls[threadIdx.x + st];
            lss[threadIdx.x] += lss[threadIdx.x + st];
        }
        __syncthreads();
    }
    if (threadIdx.x == 0) {
        part[2 * blockIdx.x]     = ls[0];
        part[2 * blockIdx.x + 1] = lss[0];
    }
}

__global__ __launch_bounds__(256) void finalize_k(const double* __restrict__ part,
                                                  const float* __restrict__ momp,
                                                  float* __restrict__ scal) {
    __shared__ double ls[256], lss[256];
    double s = 0.0, ss = 0.0;
    for (int i = threadIdx.x; i < 1024; i += 256) {
        s += part[2 * i]; ss += part[2 * i + 1];
    }
    ls[threadIdx.x] = s; lss[threadIdx.x] = ss;
    __syncthreads();
    for (int st = 128; st; st >>= 1) {
        if (threadIdx.x < st) {
            ls[threadIdx.x]  += ls[threadIdx.x + st];
            lss[threadIdx.x] += lss[threadIdx.x + st];
        }
        __syncthreads();
    }
    if (threadIdx.x == 0) {
        const double n    = (double)(B * FK * C * C);
        const double mean = ls[0] / n;
        double var        = (lss[0] - ls[0] * ls[0] / n) / (n - 1.0);
        if (var < 0.0) var = 0.0;
        const double scale = 1.0 / (sqrt(var) + 1e-4);
        scal[0] = (float)((double)momp[0] + scale);  // alpha
        scal[1] = (float)(-mean * scale);            // beta
    }
}

} // anonymous namespace

extern "C" void kernel_launch(void* const* d_in, const int* in_sizes, int n_in,
                              void* d_out, int out_size, void* d_ws, size_t ws_size,
                              hipStream_t stream) {
    (void)in_sizes; (void)n_in; (void)out_size; (void)ws_size;
    const float* x1   = (const float*)d_in[0];
    const float* x2   = (const float*)d_in[1];
    const float* kw   = (const float*)d_in[2];
    const float* qw   = (const float*)d_in[3];
    const float* momp = (const float*)d_in[4];

    char* ws = (char*)d_ws;
    unsigned short* xpad1 = (unsigned short*)ws;                   // 29,503,488
    unsigned short* xpad2 = (unsigned short*)(ws + 29503488);      // 29,503,488
    unsigned short* kwA   = (unsigned short*)(ws + 59006976);      //    663,552
    unsigned short* qwA   = (unsigned short*)(ws + 59670528);      //    663,552
    unsigned short* kcb   = (unsigned short*)(ws + 60334080);      // 28,311,552
    float*          attnT = (float*)(ws + 88645632);               // 10,616,832
    double*         part  = (double*)(ws + 99262464);              //     16,384
    float*          scal  = (float*)(ws + 99278848);               //          8
    unsigned short* qcb   = (unsigned short*)d_out;  // scratch until final conv

    // zero both padded buffers (borders must be 0; interior rewritten below)
    hipMemsetAsync(xpad1, 0, 2 * 29503488ULL, stream);

    dim3 pgrid(3, 96, 8);
    prep_x<<<pgrid, 256, 0, stream>>>(x1, xpad1);
    prep_x<<<pgrid, 256, 0, stream>>>(x2, xpad2);
    prep_w<<<2592, 256, 0, stream>>>(kw, qw, kwA, qwA);

    dim3 cgrid(96, 8);
    conv_mfma<0><<<cgrid, 384, 0, stream>>>(xpad1, kwA, nullptr, nullptr, kcb);
    conv_mfma<0><<<cgrid, 384, 0, stream>>>(xpad2, qwA, nullptr, nullptr, qcb);

    attn_k<<<dim3(36, 9, 8), 256, 0, stream>>>(kcb, qcb, attnT);
    reduce_k<<<1024, 256, 0, stream>>>(attnT, part);
    finalize_k<<<1, 256, 0, stream>>>(part, momp, scal);

    conv_mfma<1><<<cgrid, 384, 0, stream>>>(xpad1, nullptr, attnT, scal, (float*)d_out);
}

// Round 3
// 670.428 us; speedup vs baseline: 6.8440x; 1.2454x over previous
//
#include <hip/hip_runtime.h>
#include <math.h>

typedef __attribute__((ext_vector_type(8))) short s16x8;
typedef __attribute__((ext_vector_type(4))) short s16x4;
typedef __attribute__((ext_vector_type(4))) float f32x4;

typedef unsigned int u32;
typedef __attribute__((address_space(3))) u32* lds_u32p;
typedef const __attribute__((address_space(1))) u32* glb_u32p;

namespace {

constexpr int B  = 8;
constexpr int C  = 192;
constexpr int H  = 96;
constexpr int W  = 96;
constexpr int FK = 9;
constexpr int HP = 98;   // padded

__device__ inline unsigned short f2b(float f) {
    unsigned int x = __float_as_uint(f);
    x += 0x7fffu + ((x >> 16) & 1u);
    return (unsigned short)(x >> 16);
}
__device__ inline float b2f(unsigned short u) {
    return __uint_as_float(((unsigned int)u) << 16);
}

// ---------------------------------------------------------------------------
// x[b][c][96][96] f32  ->  xpadT[b][98][98][192] bf16 (channel-last, borders
// pre-zeroed by memset). LDS transpose for coalescing both sides.
// ---------------------------------------------------------------------------
__global__ __launch_bounds__(256) void prep_x(const float* __restrict__ x,
                                              unsigned short* __restrict__ xpadT) {
    __shared__ float xs[192][33];
    const int tid = threadIdx.x;
    const int x0  = blockIdx.x * 32;
    const int y   = blockIdx.y;
    const int b   = blockIdx.z;
    for (int e = tid; e < 192 * 32; e += 256) {
        const int ci = e >> 5, xx = e & 31;
        xs[ci][xx] = x[(((size_t)b * C + ci) * H + y) * W + x0 + xx];
    }
    __syncthreads();
    for (int e = tid; e < 32 * 192; e += 256) {
        const int pos = e / 192, ci = e - pos * 192;
        xpadT[(((size_t)(b * HP + y + 1)) * HP + x0 + pos + 1) * 192 + ci] = f2b(xs[ci][pos]);
    }
}

// ---------------------------------------------------------------------------
// w[co][ci][p] f32 -> wA[p][co][ci] bf16, both weight tensors in one launch
// ---------------------------------------------------------------------------
__global__ __launch_bounds__(256) void prep_w(const float* __restrict__ kw,
                                              const float* __restrict__ qw,
                                              unsigned short* __restrict__ kwA,
                                              unsigned short* __restrict__ qwA) {
    int idx = blockIdx.x * 256 + threadIdx.x;
    const int n = FK * C * C;
    const float* src = kw;
    unsigned short* dst = kwA;
    if (idx >= n) { idx -= n; src = qw; dst = qwA; }
    const int p = idx / (C * C), r = idx - p * C * C;
    const int co = r / C, ci = r - co * C;
    dst[idx] = f2b(src[((size_t)co * C + ci) * FK + p]);
}

// ---------------------------------------------------------------------------
// MFMA implicit-GEMM conv3x3. Weights wA[(b)][p][co][ci] bf16.
// Block: 6 waves = 3 co-strips(64) x 2 s-halves(48); tile = 192co x 96s (one
// output row y). Double-buffered full-row B staging via global_load_lds with
// pre-swizzled global source (LDS dest linear, XOR-swizzled reads). A frags
// batched (12 x 16B global, L2-hot) per (dy,cc).
// grid (96 y, 8 b), 384 thr
// ---------------------------------------------------------------------------
template <bool OUTF32, bool PERB>
__global__ __launch_bounds__(384, 3)
void conv_mfma(const unsigned short* __restrict__ xpadT,
               const unsigned short* __restrict__ wA,
               void* __restrict__ yout) {
    __shared__ __align__(16) char smem[2][HP * 384];   // 2 x 37632 B
    const int tid  = threadIdx.x;
    const int y    = blockIdx.x;
    const int b    = blockIdx.y;
    const int lane = tid & 63, wid = tid >> 6;
    const int wco  = wid >> 1;          // 0..2 : co strip of 64
    const int wsx  = wid & 1;           // 0..1 : s half of 48
    const int ln15 = lane & 15, kg = lane >> 4;

    const unsigned short* wp = PERB ? (wA + (size_t)b * FK * C * C) : wA;

    // B-fragment LDS addressing: pos = wsx*48 + j*16 + ln15 + dx
    // pos&7 == (ln15+dx)&7  (48 and 16 are multiples of 8)
    const int base0 = (wsx * 48 + ln15) * 384;
    int bsw3[3];
#pragma unroll
    for (int dx = 0; dx < 3; ++dx) bsw3[dx] = ((ln15 + dx) & 7) << 4;

    // staging: 2352 chunks of 16B; 6 full wave-iterations + 48-chunk tail
    int gofs[6];
#pragma unroll
    for (int it = 0; it < 6; ++it) {
        const int chunk = it * 384 + wid * 64 + lane;
        const int pos = chunk / 24, c16 = chunk - pos * 24;
        gofs[it] = pos * 384 + ((c16 * 16) ^ ((pos & 7) << 4));
    }
    int tofs = 0, tlin = 0;
    if (tid < 48) {
        const int chunk = 2304 + tid;
        const int pos = chunk / 24, c16 = chunk - pos * 24;
        tofs = pos * 384 + ((c16 * 16) ^ ((pos & 7) << 4));
        tlin = pos * 384 + c16 * 16;
    }

    auto stage = [&](int bufi, int ypad) {
        const char* rowbase = (const char*)(xpadT + ((size_t)(b * HP + ypad)) * HP * 192);
        char* lb = (char*)smem[bufi];
#pragma unroll
        for (int it = 0; it < 6; ++it) {
            __builtin_amdgcn_global_load_lds(
                (glb_u32p)(const void*)(rowbase + gofs[it]),
                (lds_u32p)(void*)(lb + it * 6144 + wid * 1024),
                16, 0, 0);
        }
        if (tid < 48) {
            const s16x8 v = *(const s16x8*)(rowbase + tofs);
            *(s16x8*)(lb + tlin) = v;
        }
    };

    f32x4 acc[4][3];
#pragma unroll
    for (int i = 0; i < 4; ++i)
#pragma unroll
        for (int j = 0; j < 3; ++j)
            acc[i][j] = (f32x4){0.f, 0.f, 0.f, 0.f};

    stage(0, y);
    asm volatile("s_waitcnt vmcnt(0)" ::: "memory");
    __syncthreads();

    for (int dy = 0; dy < 3; ++dy) {
        if (dy < 2) stage((dy + 1) & 1, y + dy + 1);

        const char* lb = (const char*)smem[dy & 1];
        const unsigned short* wpd = wp + (size_t)(3 * dy) * C * C;

        for (int cc = 0; cc < 6; ++cc) {
            s16x8 af[3][4];
#pragma unroll
            for (int dx = 0; dx < 3; ++dx)
#pragma unroll
                for (int i = 0; i < 4; ++i)
                    af[dx][i] = *(const s16x8*)(wpd +
                        ((size_t)dx * C + wco * 64 + i * 16 + ln15) * C + cc * 32 + kg * 8);
            s16x8 bv[3][3];
#pragma unroll
            for (int j = 0; j < 3; ++j)
#pragma unroll
                for (int dx = 0; dx < 3; ++dx)
                    bv[j][dx] = *(const s16x8*)(lb + base0 + j * 6144 + dx * 384 +
                                                ((cc * 64 + kg * 16) ^ bsw3[dx]));
#pragma unroll
            for (int i = 0; i < 4; ++i)
#pragma unroll
                for (int j = 0; j < 3; ++j)
#pragma unroll
                    for (int dx = 0; dx < 3; ++dx)
                        acc[i][j] = __builtin_amdgcn_mfma_f32_16x16x32_bf16(
                            af[dx][i], bv[j][dx], acc[i][j], 0, 0, 0);
        }
        if (dy < 2) {
            asm volatile("s_waitcnt vmcnt(0)" ::: "memory");
            __syncthreads();
        }
    }

    // epilogue: D col = ln15 (s), row = kg*4+reg (co within 16)
    if (!OUTF32) {
        unsigned short* yb = (unsigned short*)yout;
#pragma unroll
        for (int i = 0; i < 4; ++i)
#pragma unroll
            for (int r = 0; r < 4; ++r) {
                const int co = wco * 64 + i * 16 + kg * 4 + r;
                const size_t base = (((size_t)b * C + co) * H + y) * W;
#pragma unroll
                for (int j = 0; j < 3; ++j)
                    yb[base + wsx * 48 + j * 16 + ln15] = f2b(acc[i][j][r]);
            }
    } else {
        float* yf = (float*)yout;
#pragma unroll
        for (int i = 0; i < 4; ++i)
#pragma unroll
            for (int r = 0; r < 4; ++r) {
                const int co = wco * 64 + i * 16 + kg * 4 + r;
                const size_t base = (((size_t)b * C + co) * H + y) * W;
#pragma unroll
                for (int j = 0; j < 3; ++j)
                    yf[base + wsx * 48 + j * 16 + ln15] = acc[i][j][r];
            }
    }
}

// ---------------------------------------------------------------------------
// attn[b,p,c,o] = sum_l kc[b,c,3lh+ph,3lw+pw] * qc[b,o,...]; bf16 in, f32 out,
// written TRANSPOSED: attnT[b][p][o][c].
// ---------------------------------------------------------------------------
__global__ __launch_bounds__(256) void attn_k(const unsigned short* __restrict__ kc,
                                              const unsigned short* __restrict__ qc,
                                              float* __restrict__ attnT) {
    __shared__ float Ks[32][33];
    __shared__ float Qs[32][33];
    const int tid = threadIdx.x;
    const int ct  = (blockIdx.x / 6) * 32, ot = (blockIdx.x % 6) * 32;
    const int p   = blockIdx.y, ph = p / 3, pw = p % 3;
    const int b   = blockIdx.z;
    const int tx  = tid & 15, ty = tid >> 4;
    const int ri  = tid >> 3, rm = (tid & 7) * 4;

    float acc00 = 0.f, acc01 = 0.f, acc10 = 0.f, acc11 = 0.f;

    for (int lc = 0; lc < 32; ++lc) {
        const int row = 3 * lc + ph;
        __syncthreads();
#pragma unroll
        for (int q = 0; q < 4; ++q) {
            const int m = rm + q;
            Ks[ri][m] = b2f(kc[(((size_t)b * C + ct + ri) * H + row) * W + 3 * m + pw]);
            Qs[m][ri] = b2f(qc[(((size_t)b * C + ot + ri) * H + row) * W + 3 * m + pw]);
        }
        __syncthreads();
#pragma unroll
        for (int m = 0; m < 32; ++m) {
            const float k0 = Ks[2 * ty][m], k1 = Ks[2 * ty + 1][m];
            const float q0 = Qs[m][2 * tx], q1 = Qs[m][2 * tx + 1];
            acc00 = fmaf(k0, q0, acc00); acc01 = fmaf(k0, q1, acc01);
            acc10 = fmaf(k1, q0, acc10); acc11 = fmaf(k1, q1, acc11);
        }
    }
    float* ap = attnT + ((size_t)(b * FK + p)) * C * C;
    ap[(ot + 2 * tx) * C + ct + 2 * ty]         = acc00;
    ap[(ot + 2 * tx + 1) * C + ct + 2 * ty]     = acc01;
    ap[(ot + 2 * tx) * C + ct + 2 * ty + 1]     = acc10;
    ap[(ot + 2 * tx + 1) * C + ct + 2 * ty + 1] = acc11;
}

// ---------------------------------------------------------------------------
// global mean/std over attnT, double precision two-stage
// ---------------------------------------------------------------------------
__global__ __launch_bounds__(256) void reduce_k(const float* __restrict__ a,
                                                double* __restrict__ part) {
    const int n = B * FK * C * C;
    double s = 0.0, ss = 0.0;
    for (int i = blockIdx.x * 256 + threadIdx.x; i < n; i += 1024 * 256) {
        const double v = (double)a[i];
        s += v; ss += v * v;
    }
    __shared__ double ls[256], lss[256];
    ls[threadIdx.x] = s; lss[threadIdx.x] = ss;
    __syncthreads();
    for (int st = 128; st; st >>= 1) {
        if (threadIdx.x < st) {
            ls[threadIdx.x]  += ls[threadIdx.x + st];
            lss[threadIdx.x] += lss[threadIdx.x + st];
        }
        __syncthreads();
    }
    if (threadIdx.x == 0) {
        part[2 * blockIdx.x]     = ls[0];
        part[2 * blockIdx.x + 1] = lss[0];
    }
}

__global__ __launch_bounds__(256) void finalize_k(const double* __restrict__ part,
                                                  const float* __restrict__ momp,
                                                  float* __restrict__ scal) {
    __shared__ double ls[256], lss[256];
    double s = 0.0, ss = 0.0;
    for (int i = threadIdx.x; i < 1024; i += 256) {
        s += part[2 * i]; ss += part[2 * i + 1];
    }
    ls[threadIdx.x] = s; lss[threadIdx.x] = ss;
    __syncthreads();
    for (int st = 128; st; st >>= 1) {
        if (threadIdx.x < st) {
            ls[threadIdx.x]  += ls[threadIdx.x + st];
            lss[threadIdx.x] += lss[threadIdx.x + st];
        }
        __syncthreads();
    }
    if (threadIdx.x == 0) {
        const double n    = (double)(B * FK * C * C);
        const double mean = ls[0] / n;
        double var        = (lss[0] - ls[0] * ls[0] / n) / (n - 1.0);
        if (var < 0.0) var = 0.0;
        const double scale = 1.0 / (sqrt(var) + 1e-4);
        scal[0] = (float)((double)momp[0] + scale);  // alpha
        scal[1] = (float)(-mean * scale);            // beta
    }
}

// ---------------------------------------------------------------------------
// normW[i] = bf16(alpha * attnT[i] + beta)   (i over B*FK*C*C, layout kept)
// ---------------------------------------------------------------------------
__global__ __launch_bounds__(256) void norm_w(const float* __restrict__ a,
                                              const float* __restrict__ scal,
                                              unsigned short* __restrict__ o) {
    const float alpha = scal[0], beta = scal[1];
    const int i = (blockIdx.x * 256 + threadIdx.x) * 4;
    const float4 v = *(const float4*)(a + i);
    s16x4 r;
    r[0] = (short)f2b(fmaf(alpha, v.x, beta));
    r[1] = (short)f2b(fmaf(alpha, v.y, beta));
    r[2] = (short)f2b(fmaf(alpha, v.z, beta));
    r[3] = (short)f2b(fmaf(alpha, v.w, beta));
    *(s16x4*)(o + i) = r;
}

} // anonymous namespace

extern "C" void kernel_launch(void* const* d_in, const int* in_sizes, int n_in,
                              void* d_out, int out_size, void* d_ws, size_t ws_size,
                              hipStream_t stream) {
    (void)in_sizes; (void)n_in; (void)out_size; (void)ws_size;
    const float* x1   = (const float*)d_in[0];
    const float* x2   = (const float*)d_in[1];
    const float* kw   = (const float*)d_in[2];
    const float* qw   = (const float*)d_in[3];
    const float* momp = (const float*)d_in[4];

    char* ws = (char*)d_ws;
    unsigned short* xpad1 = (unsigned short*)ws;                   // 29,503,488
    unsigned short* xpad2 = (unsigned short*)(ws + 29503488);      // 29,503,488
    unsigned short* kwA   = (unsigned short*)(ws + 59006976);      //    663,552
    unsigned short* qwA   = (unsigned short*)(ws + 59670528);      //    663,552
    unsigned short* kcb   = (unsigned short*)(ws + 60334080);      // 28,311,552
    float*          attnT = (float*)(ws + 88645632);               // 10,616,832
    double*         part  = (double*)(ws + 99262464);              //     16,384
    float*          scal  = (float*)(ws + 99278848);               //          8
    unsigned short* normW = kcb;            // kcb dead after attn_k; 5,308,416 B
    unsigned short* qcb   = (unsigned short*)d_out;  // scratch until final conv

    hipMemsetAsync(xpad1, 0, 2 * 29503488ULL, stream);

    dim3 pgrid(3, 96, 8);
    prep_x<<<pgrid, 256, 0, stream>>>(x1, xpad1);
    prep_x<<<pgrid, 256, 0, stream>>>(x2, xpad2);
    prep_w<<<2592, 256, 0, stream>>>(kw, qw, kwA, qwA);

    dim3 cgrid(96, 8);
    conv_mfma<false, false><<<cgrid, 384, 0, stream>>>(xpad1, kwA, kcb);
    conv_mfma<false, false><<<cgrid, 384, 0, stream>>>(xpad2, qwA, qcb);

    attn_k<<<dim3(36, 9, 8), 256, 0, stream>>>(kcb, qcb, attnT);
    reduce_k<<<1024, 256, 0, stream>>>(attnT, part);
    finalize_k<<<1, 256, 0, stream>>>(part, momp, scal);

    norm_w<<<2592, 256, 0, stream>>>(attnT, scal, normW);
    conv_mfma<true, true><<<cgrid, 384, 0, stream>>>(xpad1, normW, (float*)d_out);
}

// Round 4
// 511.448 us; speedup vs baseline: 8.9714x; 1.3108x over previous
//
#include <hip/hip_runtime.h>
#include <math.h>

typedef __attribute__((ext_vector_type(8))) short s16x8;
typedef __attribute__((ext_vector_type(4))) short s16x4;
typedef __attribute__((ext_vector_type(4))) float f32x4;

typedef unsigned int u32;
typedef __attribute__((address_space(3))) u32* lds_u32p;
typedef const __attribute__((address_space(1))) u32* glb_u32p;

namespace {

constexpr int B  = 8;
constexpr int C  = 192;
constexpr int H  = 96;
constexpr int W  = 96;
constexpr int FK = 9;
constexpr int HP = 98;   // padded
constexpr int L  = 1024; // 32x32 patch grid per phase

__device__ inline unsigned short f2b(float f) {
    unsigned int x = __float_as_uint(f);
    x += 0x7fffu + ((x >> 16) & 1u);
    return (unsigned short)(x >> 16);
}

// ---------------------------------------------------------------------------
// x[b][c][96][96] f32  ->  xpadT[b][98][98][192] bf16 (channel-last, borders
// pre-zeroed by memset). LDS transpose for coalescing both sides.
// ---------------------------------------------------------------------------
__global__ __launch_bounds__(256) void prep_x(const float* __restrict__ x,
                                              unsigned short* __restrict__ xpadT) {
    __shared__ float xs[192][33];
    const int tid = threadIdx.x;
    const int x0  = blockIdx.x * 32;
    const int y   = blockIdx.y;
    const int b   = blockIdx.z;
    for (int e = tid; e < 192 * 32; e += 256) {
        const int ci = e >> 5, xx = e & 31;
        xs[ci][xx] = x[(((size_t)b * C + ci) * H + y) * W + x0 + xx];
    }
    __syncthreads();
    for (int e = tid; e < 32 * 192; e += 256) {
        const int pos = e / 192, ci = e - pos * 192;
        xpadT[(((size_t)(b * HP + y + 1)) * HP + x0 + pos + 1) * 192 + ci] = f2b(xs[ci][pos]);
    }
}

// ---------------------------------------------------------------------------
// w[co][ci][p] f32 -> wA[p][co][ci] bf16, both weight tensors in one launch
// ---------------------------------------------------------------------------
__global__ __launch_bounds__(256) void prep_w(const float* __restrict__ kw,
                                              const float* __restrict__ qw,
                                              unsigned short* __restrict__ kwA,
                                              unsigned short* __restrict__ qwA) {
    int idx = blockIdx.x * 256 + threadIdx.x;
    const int n = FK * C * C;
    const float* src = kw;
    unsigned short* dst = kwA;
    if (idx >= n) { idx -= n; src = qw; dst = qwA; }
    const int p = idx / (C * C), r = idx - p * C * C;
    const int co = r / C, ci = r - co * C;
    dst[idx] = f2b(src[((size_t)co * C + ci) * FK + p]);
}

// ---------------------------------------------------------------------------
// MFMA implicit-GEMM conv3x3. Weights wA[(b)][p][co][ci] bf16.
// Block: 6 waves = 3 co-strips(64) x 2 s-halves(48); tile = 192co x 96s (one
// output row y). Double-buffered full-row B staging via global_load_lds with
// pre-swizzled global source. A frags batched (12 x 16B global, L2-hot).
// OUTF32=false: write bf16 in PHASE layout kcS[b][3*(y%3)+(x%3)][co][lh*32+lw]
// OUTF32=true : write f32 NCHW (final output)
// grid (96 y, 8 b), 384 thr
// ---------------------------------------------------------------------------
template <bool OUTF32, bool PERB>
__global__ __launch_bounds__(384, 3)
void conv_mfma(const unsigned short* __restrict__ xpadT,
               const unsigned short* __restrict__ wA,
               void* __restrict__ yout) {
    __shared__ __align__(16) char smem[2][HP * 384];   // 2 x 37632 B
    const int tid  = threadIdx.x;
    const int y    = blockIdx.x;
    const int b    = blockIdx.y;
    const int lane = tid & 63, wid = tid >> 6;
    const int wco  = wid >> 1;          // 0..2 : co strip of 64
    const int wsx  = wid & 1;           // 0..1 : s half of 48
    const int ln15 = lane & 15, kg = lane >> 4;

    const unsigned short* wp = PERB ? (wA + (size_t)b * FK * C * C) : wA;

    const int base0 = (wsx * 48 + ln15) * 384;
    int bsw3[3];
#pragma unroll
    for (int dx = 0; dx < 3; ++dx) bsw3[dx] = ((ln15 + dx) & 7) << 4;

    // staging: 2352 chunks of 16B; 6 full wave-iterations + 48-chunk tail
    int gofs[6];
#pragma unroll
    for (int it = 0; it < 6; ++it) {
        const int chunk = it * 384 + wid * 64 + lane;
        const int pos = chunk / 24, c16 = chunk - pos * 24;
        gofs[it] = pos * 384 + ((c16 * 16) ^ ((pos & 7) << 4));
    }
    int tofs = 0, tlin = 0;
    if (tid < 48) {
        const int chunk = 2304 + tid;
        const int pos = chunk / 24, c16 = chunk - pos * 24;
        tofs = pos * 384 + ((c16 * 16) ^ ((pos & 7) << 4));
        tlin = pos * 384 + c16 * 16;
    }

    auto stage = [&](int bufi, int ypad) {
        const char* rowbase = (const char*)(xpadT + ((size_t)(b * HP + ypad)) * HP * 192);
        char* lb = (char*)smem[bufi];
#pragma unroll
        for (int it = 0; it < 6; ++it) {
            __builtin_amdgcn_global_load_lds(
                (glb_u32p)(const void*)(rowbase + gofs[it]),
                (lds_u32p)(void*)(lb + it * 6144 + wid * 1024),
                16, 0, 0);
        }
        if (tid < 48) {
            const s16x8 v = *(const s16x8*)(rowbase + tofs);
            *(s16x8*)(lb + tlin) = v;
        }
    };

    f32x4 acc[4][3];
#pragma unroll
    for (int i = 0; i < 4; ++i)
#pragma unroll
        for (int j = 0; j < 3; ++j)
            acc[i][j] = (f32x4){0.f, 0.f, 0.f, 0.f};

    stage(0, y);
    asm volatile("s_waitcnt vmcnt(0)" ::: "memory");
    __syncthreads();

    for (int dy = 0; dy < 3; ++dy) {
        if (dy < 2) stage((dy + 1) & 1, y + dy + 1);

        const char* lb = (const char*)smem[dy & 1];
        const unsigned short* wpd = wp + (size_t)(3 * dy) * C * C;

        for (int cc = 0; cc < 6; ++cc) {
            s16x8 af[3][4];
#pragma unroll
            for (int dx = 0; dx < 3; ++dx)
#pragma unroll
                for (int i = 0; i < 4; ++i)
                    af[dx][i] = *(const s16x8*)(wpd +
                        ((size_t)dx * C + wco * 64 + i * 16 + ln15) * C + cc * 32 + kg * 8);
            s16x8 bv[3][3];
#pragma unroll
            for (int j = 0; j < 3; ++j)
#pragma unroll
                for (int dx = 0; dx < 3; ++dx)
                    bv[j][dx] = *(const s16x8*)(lb + base0 + j * 6144 + dx * 384 +
                                                ((cc * 64 + kg * 16) ^ bsw3[dx]));
#pragma unroll
            for (int i = 0; i < 4; ++i)
#pragma unroll
                for (int j = 0; j < 3; ++j)
#pragma unroll
                    for (int dx = 0; dx < 3; ++dx)
                        acc[i][j] = __builtin_amdgcn_mfma_f32_16x16x32_bf16(
                            af[dx][i], bv[j][dx], acc[i][j], 0, 0, 0);
        }
        if (dy < 2) {
            asm volatile("s_waitcnt vmcnt(0)" ::: "memory");
            __syncthreads();
        }
    }

    // epilogue: D col = ln15 (s), row = kg*4+reg (co within 16)
    if (!OUTF32) {
        // phase layout: dst[((b*9 + (y%3)*3 + s%3)*192 + co)*1024 + (y/3)*32 + s/3]
        unsigned short* yb = (unsigned short*)yout;
        const int ph = y % 3, lh = y / 3;
        int poff[3];
#pragma unroll
        for (int j = 0; j < 3; ++j) {
            const int s  = wsx * 48 + j * 16 + ln15;
            const int pw = s % 3, lw = s / 3;
            poff[j] = ((b * FK + ph * 3 + pw) * C) * L + lh * 32 + lw;
        }
#pragma unroll
        for (int i = 0; i < 4; ++i)
#pragma unroll
            for (int r = 0; r < 4; ++r) {
                const int co = wco * 64 + i * 16 + kg * 4 + r;
#pragma unroll
                for (int j = 0; j < 3; ++j)
                    yb[(size_t)poff[j] + co * L] = f2b(acc[i][j][r]);
            }
    } else {
        float* yf = (float*)yout;
#pragma unroll
        for (int i = 0; i < 4; ++i)
#pragma unroll
            for (int r = 0; r < 4; ++r) {
                const int co = wco * 64 + i * 16 + kg * 4 + r;
                const size_t base = (((size_t)b * C + co) * H + y) * W;
#pragma unroll
                for (int j = 0; j < 3; ++j)
                    yf[base + wsx * 48 + j * 16 + ln15] = acc[i][j][r];
            }
    }
}

// ---------------------------------------------------------------------------
// attn MFMA: per (b,phase) GEMM D[c][o] = sum_k Kc[c][k]*Qc[o][k], K=1024.
// Block = 96c x 96o quarter (grid.x: bit0=o-half, bit1=c-half), 4 waves 48x48.
// BK=64 double-buffered LDS staging via global_load_lds, pre-swizzled source.
// Epilogue: writes attnT[b][p][o][c] f32 + fused f64 sum/ssq partials.
// grid (4, 9, 8), 256 thr
// ---------------------------------------------------------------------------
__global__ __launch_bounds__(256, 3)
void attn_mfma(const unsigned short* __restrict__ kcS,
               const unsigned short* __restrict__ qcS,
               float* __restrict__ attnT,
               double* __restrict__ part) {
    __shared__ __align__(16) char smem[2][24576];   // [buf][A 12KB | B 12KB]
    const int tid  = threadIdx.x;
    const int lane = tid & 63, wid = tid >> 6;
    const int wq   = wid & 1, wp = wid >> 1;        // wave: o-half, c-half (48)
    const int ln15 = lane & 15, kg = lane >> 4;
    const int of   = blockIdx.x & 1, cf = blockIdx.x >> 1;
    const int p    = blockIdx.y, b = blockIdx.z;

    const char* Abase = (const char*)(kcS + ((size_t)(b * FK + p) * C + cf * 96) * L);
    const char* Bbase = (const char*)(qcS + ((size_t)(b * FK + p) * C + of * 96) * L);

    // staging geometry: tile 96 rows x 128B; 768 chunks of 16B per matrix
    int gofs[3];
#pragma unroll
    for (int it = 0; it < 3; ++it) {
        const int chunk = it * 256 + tid;
        const int row = chunk >> 3, c16 = chunk & 7;
        gofs[it] = row * 2048 + ((c16 * 16) ^ ((row & 7) << 4));
    }

    auto stage = [&](int bufi, int t) {
        const char* Ab = Abase + t * 128;
        const char* Bb = Bbase + t * 128;
        char* lb = (char*)smem[bufi];
#pragma unroll
        for (int it = 0; it < 3; ++it)
            __builtin_amdgcn_global_load_lds(
                (glb_u32p)(const void*)(Ab + gofs[it]),
                (lds_u32p)(void*)(lb + it * 4096 + wid * 1024), 16, 0, 0);
#pragma unroll
        for (int it = 0; it < 3; ++it)
            __builtin_amdgcn_global_load_lds(
                (glb_u32p)(const void*)(Bb + gofs[it]),
                (lds_u32p)(void*)(lb + 12288 + it * 4096 + wid * 1024), 16, 0, 0);
    };

    f32x4 acc[3][3];
#pragma unroll
    for (int i = 0; i < 3; ++i)
#pragma unroll
        for (int j = 0; j < 3; ++j)
            acc[i][j] = (f32x4){0.f, 0.f, 0.f, 0.f};

    stage(0, 0);
    asm volatile("s_waitcnt vmcnt(0)" ::: "memory");
    __syncthreads();

    for (int t = 0; t < 16; ++t) {
        if (t < 15) stage((t + 1) & 1, t + 1);
        const char* lb = (const char*)smem[t & 1];
#pragma unroll
        for (int ks = 0; ks < 2; ++ks) {
            s16x8 af[3], bf[3];
#pragma unroll
            for (int i = 0; i < 3; ++i) {
                const int row = wp * 48 + i * 16 + ln15;
                af[i] = *(const s16x8*)(lb + row * 128 +
                                        ((ks * 64 + kg * 16) ^ ((row & 7) << 4)));
            }
#pragma unroll
            for (int j = 0; j < 3; ++j) {
                const int row = wq * 48 + j * 16 + ln15;
                bf[j] = *(const s16x8*)(lb + 12288 + row * 128 +
                                        ((ks * 64 + kg * 16) ^ ((row & 7) << 4)));
            }
#pragma unroll
            for (int i = 0; i < 3; ++i)
#pragma unroll
                for (int j = 0; j < 3; ++j)
                    acc[i][j] = __builtin_amdgcn_mfma_f32_16x16x32_bf16(
                        af[i], bf[j], acc[i][j], 0, 0, 0);
        }
        if (t < 15) {
            asm volatile("s_waitcnt vmcnt(0)" ::: "memory");
            __syncthreads();
        }
    }

    // fused partial mean/ssq (f64) — reuse LDS after barrier
    __syncthreads();
    double s = 0.0, ss = 0.0;
#pragma unroll
    for (int i = 0; i < 3; ++i)
#pragma unroll
        for (int j = 0; j < 3; ++j)
#pragma unroll
            for (int r = 0; r < 4; ++r) {
                const double v = (double)acc[i][j][r];
                s += v; ss += v * v;
            }
    double* ls  = (double*)&smem[0][0];
    double* lss = ls + 256;
    ls[tid] = s; lss[tid] = ss;
    __syncthreads();
    for (int st = 128; st; st >>= 1) {
        if (tid < st) { ls[tid] += ls[tid + st]; lss[tid] += lss[tid + st]; }
        __syncthreads();
    }
    if (tid == 0) {
        const int bf_ = ((b * FK + p) << 2) + blockIdx.x;
        part[2 * bf_]     = ls[0];
        part[2 * bf_ + 1] = lss[0];
    }

    // store attnT[b][p][o][c]: lane holds D[c=i*16+kg*4+r][o=j*16+ln15]
    float* ap = attnT + (size_t)(b * FK + p) * C * C;
#pragma unroll
    for (int i = 0; i < 3; ++i) {
        const int c0 = cf * 96 + wp * 48 + i * 16 + kg * 4;
#pragma unroll
        for (int j = 0; j < 3; ++j) {
            const int o = of * 96 + wq * 48 + j * 16 + ln15;
            *(f32x4*)(ap + o * C + c0) = acc[i][j];
        }
    }
}

__global__ __launch_bounds__(256) void finalize_k(const double* __restrict__ part,
                                                  const float* __restrict__ momp,
                                                  float* __restrict__ scal) {
    __shared__ double ls[256], lss[256];
    double s = 0.0, ss = 0.0;
    for (int i = threadIdx.x; i < 288; i += 256) {
        s += part[2 * i]; ss += part[2 * i + 1];
    }
    ls[threadIdx.x] = s; lss[threadIdx.x] = ss;
    __syncthreads();
    for (int st = 128; st; st >>= 1) {
        if (threadIdx.x < st) {
            ls[threadIdx.x]  += ls[threadIdx.x + st];
            lss[threadIdx.x] += lss[threadIdx.x + st];
        }
        __syncthreads();
    }
    if (threadIdx.x == 0) {
        const double n    = (double)(B * FK * C * C);
        const double mean = ls[0] / n;
        double var        = (lss[0] - ls[0] * ls[0] / n) / (n - 1.0);
        if (var < 0.0) var = 0.0;
        const double scale = 1.0 / (sqrt(var) + 1e-4);
        scal[0] = (float)((double)momp[0] + scale);  // alpha
        scal[1] = (float)(-mean * scale);            // beta
    }
}

// ---------------------------------------------------------------------------
// normW[i] = bf16(alpha * attnT[i] + beta)
// ---------------------------------------------------------------------------
__global__ __launch_bounds__(256) void norm_w(const float* __restrict__ a,
                                              const float* __restrict__ scal,
                                              unsigned short* __restrict__ o) {
    const float alpha = scal[0], beta = scal[1];
    const int i = (blockIdx.x * 256 + threadIdx.x) * 4;
    const float4 v = *(const float4*)(a + i);
    s16x4 r;
    r[0] = (short)f2b(fmaf(alpha, v.x, beta));
    r[1] = (short)f2b(fmaf(alpha, v.y, beta));
    r[2] = (short)f2b(fmaf(alpha, v.z, beta));
    r[3] = (short)f2b(fmaf(alpha, v.w, beta));
    *(s16x4*)(o + i) = r;
}

} // anonymous namespace

extern "C" void kernel_launch(void* const* d_in, const int* in_sizes, int n_in,
                              void* d_out, int out_size, void* d_ws, size_t ws_size,
                              hipStream_t stream) {
    (void)in_sizes; (void)n_in; (void)out_size; (void)ws_size;
    const float* x1   = (const float*)d_in[0];
    const float* x2   = (const float*)d_in[1];
    const float* kw   = (const float*)d_in[2];
    const float* qw   = (const float*)d_in[3];
    const float* momp = (const float*)d_in[4];

    char* ws = (char*)d_ws;
    unsigned short* xpad1 = (unsigned short*)ws;                   // 29,503,488
    unsigned short* xpad2 = (unsigned short*)(ws + 29503488);      // 29,503,488
    unsigned short* kwA   = (unsigned short*)(ws + 59006976);      //    663,552
    unsigned short* qwA   = (unsigned short*)(ws + 59670528);      //    663,552
    unsigned short* kcS   = (unsigned short*)(ws + 60334080);      // 28,311,552
    float*          attnT = (float*)(ws + 88645632);               // 10,616,832
    double*         part  = (double*)(ws + 99262464);              //      4,608
    float*          scal  = (float*)(ws + 99278848);               //          8
    unsigned short* normW = kcS;            // kcS dead after attn; 5,308,416 B
    unsigned short* qcS   = (unsigned short*)d_out;  // scratch until final conv

    hipMemsetAsync(xpad1, 0, 2 * 29503488ULL, stream);

    dim3 pgrid(3, 96, 8);
    prep_x<<<pgrid, 256, 0, stream>>>(x1, xpad1);
    prep_x<<<pgrid, 256, 0, stream>>>(x2, xpad2);
    prep_w<<<2592, 256, 0, stream>>>(kw, qw, kwA, qwA);

    dim3 cgrid(96, 8);
    conv_mfma<false, false><<<cgrid, 384, 0, stream>>>(xpad1, kwA, kcS);
    conv_mfma<false, false><<<cgrid, 384, 0, stream>>>(xpad2, qwA, qcS);

    attn_mfma<<<dim3(4, 9, 8), 256, 0, stream>>>(kcS, qcS, attnT, part);
    finalize_k<<<1, 256, 0, stream>>>(part, momp, scal);

    norm_w<<<2592, 256, 0, stream>>>(attnT, scal, normW);
    conv_mfma<true, true><<<cgrid, 384, 0, stream>>>(xpad1, normW, (float*)d_out);
}

// Round 5
// 470.841 us; speedup vs baseline: 9.7451x; 1.0862x over previous
//
#include <hip/hip_runtime.h>
#include <math.h>

typedef __attribute__((ext_vector_type(8))) short s16x8;
typedef __attribute__((ext_vector_type(4))) short s16x4;
typedef __attribute__((ext_vector_type(4))) float f32x4;

typedef unsigned int u32;
typedef __attribute__((address_space(3))) u32* lds_u32p;
typedef const __attribute__((address_space(1))) u32* glb_u32p;

namespace {

constexpr int B  = 8;
constexpr int C  = 192;
constexpr int H  = 96;
constexpr int W  = 96;
constexpr int FK = 9;
constexpr int HP = 98;    // padded
constexpr int L  = 1024;  // 32x32 patch grid per phase
constexpr int WCHUNK = FK * 12 * 6;          // 648 packed 1KB chunks per tensor
constexpr int WELEM  = WCHUNK * 512;         // 331776 bf16 elements

__device__ inline unsigned short f2b(float f) {
    unsigned int x = __float_as_uint(f);
    x += 0x7fffu + ((x >> 16) & 1u);
    return (unsigned short)(x >> 16);
}

// ---------------------------------------------------------------------------
// x[b][c][96][96] f32 -> xpadT[b][98][98][192] bf16 (borders pre-zeroed)
// ---------------------------------------------------------------------------
__global__ __launch_bounds__(256) void prep_x(const float* __restrict__ x,
                                              unsigned short* __restrict__ xpadT) {
    __shared__ float xs[192][33];
    const int tid = threadIdx.x;
    const int x0  = blockIdx.x * 32;
    const int y   = blockIdx.y;
    const int b   = blockIdx.z;
    for (int e = tid; e < 192 * 32; e += 256) {
        const int ci = e >> 5, xx = e & 31;
        xs[ci][xx] = x[(((size_t)b * C + ci) * H + y) * W + x0 + xx];
    }
    __syncthreads();
    for (int e = tid; e < 32 * 192; e += 256) {
        const int pos = e / 192, ci = e - pos * 192;
        xpadT[(((size_t)(b * HP + y + 1)) * HP + x0 + pos + 1) * 192 + ci] = f2b(xs[ci][pos]);
    }
}

// ---------------------------------------------------------------------------
// pack weights into fragment-linear layout:
//   dst[(((p*12 + cot)*6 + cc))*512 + lane*8 + t]  = w[co][ci][p]
//   lane = kg*16 + r15; co = cot*16 + r15; ci = cc*32 + kg*8 + t
// ---------------------------------------------------------------------------
__global__ __launch_bounds__(256) void prep_w(const float* __restrict__ kw,
                                              const float* __restrict__ qw,
                                              unsigned short* __restrict__ kwA,
                                              unsigned short* __restrict__ qwA) {
    int idx = blockIdx.x * 256 + threadIdx.x;
    const float* src = kw;
    unsigned short* dst = kwA;
    if (idx >= WELEM) { idx -= WELEM; src = qw; dst = qwA; }
    const int chunk = idx >> 9, within = idx & 511;
    const int lane = within >> 3, t = within & 7;
    const int kg = lane >> 4, r15 = lane & 15;
    const int cc = chunk % 6, c2 = chunk / 6;
    const int cot = c2 % 12, p = c2 / 12;
    const int co = cot * 16 + r15;
    const int ci = cc * 32 + kg * 8 + t;
    dst[idx] = f2b(src[((size_t)co * C + ci) * FK + p]);
}

// ---------------------------------------------------------------------------
// MFMA implicit-GEMM conv3x3, 2 output rows per block.
// Block: 512 thr = 8 waves: wy=wid&1 (out row), ws=(wid>>1)&1 (s-half),
// wc=wid>>2 (co 48-strip within the block's 96-co half). Wave = 48co x 48s.
// Single LDS row buffer (37.6 KB), staged per input row via global_load_lds
// with pre-swizzled global source; packed A frags (coalesced 1KB/wave).
// grid (48 ypair, 2 cohalf, 8 b)
// ---------------------------------------------------------------------------
template <bool OUTF32, bool PERB>
__global__ __launch_bounds__(512, 3)
void conv_mfma(const unsigned short* __restrict__ xpadT,
               const unsigned short* __restrict__ wA,
               void* __restrict__ yout) {
    __shared__ __align__(16) char smem[HP * 384];   // 37632 B
    const int tid  = threadIdx.x;
    const int y0   = blockIdx.x * 2;
    const int ch   = blockIdx.y;        // co half (96)
    const int b    = blockIdx.z;
    const int lane = tid & 63, wid = tid >> 6;
    const int wy   = wid & 1, ws = (wid >> 1) & 1, wc = wid >> 2;
    const int ln15 = lane & 15, kg = lane >> 4;

    const unsigned short* wp = PERB ? (wA + (size_t)b * WELEM) : wA;

    // staging address precompute: 2352 chunks of 16B
    int gfull[4];
#pragma unroll
    for (int it = 0; it < 4; ++it) {
        const int chunk = it * 512 + tid;
        const int pos = chunk / 24, c16 = chunk - pos * 24;
        gfull[it] = pos * 384 + ((c16 * 16) ^ ((pos & 7) << 4));
    }
    int gtail = 0;
    if (tid < 304) {
        const int chunk = 2048 + tid;
        const int pos = chunk / 24, c16 = chunk - pos * 24;
        gtail = pos * 384 + ((c16 * 16) ^ ((pos & 7) << 4));
    }

    auto stage = [&](int prow) {
        const char* rowbase = (const char*)(xpadT + ((size_t)(b * HP + prow)) * HP * 192);
#pragma unroll
        for (int it = 0; it < 4; ++it)
            __builtin_amdgcn_global_load_lds(
                (glb_u32p)(const void*)(rowbase + gfull[it]),
                (lds_u32p)(void*)(smem + it * 8192 + wid * 1024), 16, 0, 0);
        if (tid < 304)
            __builtin_amdgcn_global_load_lds(
                (glb_u32p)(const void*)(rowbase + gtail),
                (lds_u32p)(void*)(smem + 32768 + wid * 1024), 16, 0, 0);
    };

    f32x4 acc[3][3];
#pragma unroll
    for (int i = 0; i < 3; ++i)
#pragma unroll
        for (int j = 0; j < 3; ++j)
            acc[i][j] = (f32x4){0.f, 0.f, 0.f, 0.f};

    for (int r = 0; r < 4; ++r) {
        if (r) __syncthreads();          // prior compute done with LDS
        stage(y0 + r);
        asm volatile("s_waitcnt vmcnt(0)" ::: "memory");
        __syncthreads();

        const int ty = r - wy;           // tap row for this wave's output y
        if ((unsigned)ty < 3u) {
            for (int cc = 0; cc < 6; ++cc) {
                s16x8 af[3][3];
#pragma unroll
                for (int dx = 0; dx < 3; ++dx)
#pragma unroll
                    for (int i = 0; i < 3; ++i) {
                        const int chunkid =
                            ((3 * ty + dx) * 12 + ch * 6 + wc * 3 + i) * 6 + cc;
                        af[dx][i] = *(const s16x8*)(wp + (size_t)chunkid * 512 + lane * 8);
                    }
                s16x8 bv[3][3];
#pragma unroll
                for (int j = 0; j < 3; ++j)
#pragma unroll
                    for (int dx = 0; dx < 3; ++dx) {
                        const int pos = ws * 48 + j * 16 + ln15 + dx;
                        bv[j][dx] = *(const s16x8*)(smem + pos * 384 +
                                        ((cc * 64 + kg * 16) ^ ((pos & 7) << 4)));
                    }
#pragma unroll
                for (int i = 0; i < 3; ++i)
#pragma unroll
                    for (int j = 0; j < 3; ++j)
#pragma unroll
                        for (int dx = 0; dx < 3; ++dx)
                            acc[i][j] = __builtin_amdgcn_mfma_f32_16x16x32_bf16(
                                af[dx][i], bv[j][dx], acc[i][j], 0, 0, 0);
            }
        }
    }

    const int y = y0 + wy;
    if (!OUTF32) {
        // phase layout: dst[((b*9 + (y%3)*3 + s%3)*192 + co)*1024 + (y/3)*32 + s/3]
        unsigned short* yb = (unsigned short*)yout;
        const int ph = y % 3, lh = y / 3;
        int poff[3];
#pragma unroll
        for (int j = 0; j < 3; ++j) {
            const int s  = ws * 48 + j * 16 + ln15;
            const int pw = s % 3, lw = s / 3;
            poff[j] = ((b * FK + ph * 3 + pw) * C) * L + lh * 32 + lw;
        }
#pragma unroll
        for (int i = 0; i < 3; ++i)
#pragma unroll
            for (int rr = 0; rr < 4; ++rr) {
                const int co = ch * 96 + wc * 48 + i * 16 + kg * 4 + rr;
#pragma unroll
                for (int j = 0; j < 3; ++j)
                    yb[(size_t)poff[j] + co * L] = f2b(acc[i][j][rr]);
            }
    } else {
        float* yf = (float*)yout;
#pragma unroll
        for (int i = 0; i < 3; ++i)
#pragma unroll
            for (int rr = 0; rr < 4; ++rr) {
                const int co = ch * 96 + wc * 48 + i * 16 + kg * 4 + rr;
                const size_t base = (((size_t)b * C + co) * H + y) * W;
#pragma unroll
                for (int j = 0; j < 3; ++j)
                    yf[base + ws * 48 + j * 16 + ln15] = acc[i][j][rr];
            }
    }
}

// ---------------------------------------------------------------------------
// attn MFMA: per (b,phase) GEMM D[c][o] = sum_k Kc[c][k]*Qc[o][k], K=1024.
// Block = 96c x 96o quarter, 4 waves 48x48. BK=64 double-buffered staging.
// Epilogue: attnT[b][p][o][c] f32 + fused f64 sum/ssq partials.
// grid (4, 9, 8), 256 thr
// ---------------------------------------------------------------------------
__global__ __launch_bounds__(256, 3)
void attn_mfma(const unsigned short* __restrict__ kcS,
               const unsigned short* __restrict__ qcS,
               float* __restrict__ attnT,
               double* __restrict__ part) {
    __shared__ __align__(16) char smem[2][24576];   // [buf][A 12KB | B 12KB]
    const int tid  = threadIdx.x;
    const int lane = tid & 63, wid = tid >> 6;
    const int wq   = wid & 1, wp = wid >> 1;
    const int ln15 = lane & 15, kg = lane >> 4;
    const int of   = blockIdx.x & 1, cf = blockIdx.x >> 1;
    const int p    = blockIdx.y, b = blockIdx.z;

    const char* Abase = (const char*)(kcS + ((size_t)(b * FK + p) * C + cf * 96) * L);
    const char* Bbase = (const char*)(qcS + ((size_t)(b * FK + p) * C + of * 96) * L);

    int gofs[3];
#pragma unroll
    for (int it = 0; it < 3; ++it) {
        const int chunk = it * 256 + tid;
        const int row = chunk >> 3, c16 = chunk & 7;
        gofs[it] = row * 2048 + ((c16 * 16) ^ ((row & 7) << 4));
    }

    auto stage = [&](int bufi, int t) {
        const char* Ab = Abase + t * 128;
        const char* Bb = Bbase + t * 128;
        char* lb = (char*)smem[bufi];
#pragma unroll
        for (int it = 0; it < 3; ++it)
            __builtin_amdgcn_global_load_lds(
                (glb_u32p)(const void*)(Ab + gofs[it]),
                (lds_u32p)(void*)(lb + it * 4096 + wid * 1024), 16, 0, 0);
#pragma unroll
        for (int it = 0; it < 3; ++it)
            __builtin_amdgcn_global_load_lds(
                (glb_u32p)(const void*)(Bb + gofs[it]),
                (lds_u32p)(void*)(lb + 12288 + it * 4096 + wid * 1024), 16, 0, 0);
    };

    f32x4 acc[3][3];
#pragma unroll
    for (int i = 0; i < 3; ++i)
#pragma unroll
        for (int j = 0; j < 3; ++j)
            acc[i][j] = (f32x4){0.f, 0.f, 0.f, 0.f};

    stage(0, 0);
    asm volatile("s_waitcnt vmcnt(0)" ::: "memory");
    __syncthreads();

    for (int t = 0; t < 16; ++t) {
        if (t < 15) stage((t + 1) & 1, t + 1);
        const char* lb = (const char*)smem[t & 1];
#pragma unroll
        for (int ks = 0; ks < 2; ++ks) {
            s16x8 af[3], bf[3];
#pragma unroll
            for (int i = 0; i < 3; ++i) {
                const int row = wp * 48 + i * 16 + ln15;
                af[i] = *(const s16x8*)(lb + row * 128 +
                                        ((ks * 64 + kg * 16) ^ ((row & 7) << 4)));
            }
#pragma unroll
            for (int j = 0; j < 3; ++j) {
                const int row = wq * 48 + j * 16 + ln15;
                bf[j] = *(const s16x8*)(lb + 12288 + row * 128 +
                                        ((ks * 64 + kg * 16) ^ ((row & 7) << 4)));
            }
#pragma unroll
            for (int i = 0; i < 3; ++i)
#pragma unroll
                for (int j = 0; j < 3; ++j)
                    acc[i][j] = __builtin_amdgcn_mfma_f32_16x16x32_bf16(
                        af[i], bf[j], acc[i][j], 0, 0, 0);
        }
        if (t < 15) {
            asm volatile("s_waitcnt vmcnt(0)" ::: "memory");
            __syncthreads();
        }
    }

    __syncthreads();
    double s = 0.0, ss = 0.0;
#pragma unroll
    for (int i = 0; i < 3; ++i)
#pragma unroll
        for (int j = 0; j < 3; ++j)
#pragma unroll
            for (int r = 0; r < 4; ++r) {
                const double v = (double)acc[i][j][r];
                s += v; ss += v * v;
            }
    double* ls  = (double*)&smem[0][0];
    double* lss = ls + 256;
    ls[tid] = s; lss[tid] = ss;
    __syncthreads();
    for (int st = 128; st; st >>= 1) {
        if (tid < st) { ls[tid] += ls[tid + st]; lss[tid] += lss[tid + st]; }
        __syncthreads();
    }
    if (tid == 0) {
        const int bf_ = ((b * FK + p) << 2) + blockIdx.x;
        part[2 * bf_]     = ls[0];
        part[2 * bf_ + 1] = lss[0];
    }

    float* ap = attnT + (size_t)(b * FK + p) * C * C;
#pragma unroll
    for (int i = 0; i < 3; ++i) {
        const int c0 = cf * 96 + wp * 48 + i * 16 + kg * 4;
#pragma unroll
        for (int j = 0; j < 3; ++j) {
            const int o = of * 96 + wq * 48 + j * 16 + ln15;
            *(f32x4*)(ap + o * C + c0) = acc[i][j];
        }
    }
}

__global__ __launch_bounds__(256) void finalize_k(const double* __restrict__ part,
                                                  const float* __restrict__ momp,
                                                  float* __restrict__ scal) {
    __shared__ double ls[256], lss[256];
    double s = 0.0, ss = 0.0;
    for (int i = threadIdx.x; i < 288; i += 256) {
        s += part[2 * i]; ss += part[2 * i + 1];
    }
    ls[threadIdx.x] = s; lss[threadIdx.x] = ss;
    __syncthreads();
    for (int st = 128; st; st >>= 1) {
        if (threadIdx.x < st) {
            ls[threadIdx.x]  += ls[threadIdx.x + st];
            lss[threadIdx.x] += lss[threadIdx.x + st];
        }
        __syncthreads();
    }
    if (threadIdx.x == 0) {
        const double n    = (double)(B * FK * C * C);
        const double mean = ls[0] / n;
        double var        = (lss[0] - ls[0] * ls[0] / n) / (n - 1.0);
        if (var < 0.0) var = 0.0;
        const double scale = 1.0 / (sqrt(var) + 1e-4);
        scal[0] = (float)((double)momp[0] + scale);  // alpha
        scal[1] = (float)(-mean * scale);            // beta
    }
}

// ---------------------------------------------------------------------------
// normW packed: out[b][chunk][lane][t] = bf16(alpha*attnT[b][p][co][ci]+beta)
// chunk = (p*12 + cot)*6 + cc; co = cot*16 + (lane&15); ci = cc*32+(lane>>4)*8+t
// ---------------------------------------------------------------------------
__global__ __launch_bounds__(256) void norm_w(const float* __restrict__ attnT,
                                              const float* __restrict__ scal,
                                              unsigned short* __restrict__ o) {
    const float alpha = scal[0], beta = scal[1];
    const int g = (blockIdx.x * 256 + threadIdx.x) * 4;
    const int chunk = g >> 9, within = g & 511;
    const int lane = within >> 3, t0 = within & 7;
    const int cc = chunk % 6, c2 = chunk / 6;
    const int cot = c2 % 12, pb = c2 / 12;
    const int p = pb % FK, b = pb / FK;
    const int co = cot * 16 + (lane & 15);
    const int ci = cc * 32 + (lane >> 4) * 8 + t0;
    const float4 v = *(const float4*)(attnT + (((size_t)(b * FK + p) * C + co) * C + ci));
    s16x4 r;
    r[0] = (short)f2b(fmaf(alpha, v.x, beta));
    r[1] = (short)f2b(fmaf(alpha, v.y, beta));
    r[2] = (short)f2b(fmaf(alpha, v.z, beta));
    r[3] = (short)f2b(fmaf(alpha, v.w, beta));
    *(s16x4*)(o + g) = r;
}

} // anonymous namespace

extern "C" void kernel_launch(void* const* d_in, const int* in_sizes, int n_in,
                              void* d_out, int out_size, void* d_ws, size_t ws_size,
                              hipStream_t stream) {
    (void)in_sizes; (void)n_in; (void)out_size; (void)ws_size;
    const float* x1   = (const float*)d_in[0];
    const float* x2   = (const float*)d_in[1];
    const float* kw   = (const float*)d_in[2];
    const float* qw   = (const float*)d_in[3];
    const float* momp = (const float*)d_in[4];

    char* ws = (char*)d_ws;
    unsigned short* xpad1 = (unsigned short*)ws;                   // 29,503,488
    unsigned short* xpad2 = (unsigned short*)(ws + 29503488);      // 29,503,488
    unsigned short* kwA   = (unsigned short*)(ws + 59006976);      //    663,552
    unsigned short* qwA   = (unsigned short*)(ws + 59670528);      //    663,552
    unsigned short* kcS   = (unsigned short*)(ws + 60334080);      // 28,311,552
    float*          attnT = (float*)(ws + 88645632);               // 10,616,832
    double*         part  = (double*)(ws + 99262464);              //      4,608
    float*          scal  = (float*)(ws + 99278848);               //          8
    unsigned short* normW = kcS;            // kcS dead after attn; 5,308,416 B
    unsigned short* qcS   = (unsigned short*)d_out;  // scratch until final conv

    hipMemsetAsync(xpad1, 0, 2 * 29503488ULL, stream);

    dim3 pgrid(3, 96, 8);
    prep_x<<<pgrid, 256, 0, stream>>>(x1, xpad1);
    prep_x<<<pgrid, 256, 0, stream>>>(x2, xpad2);
    prep_w<<<2592, 256, 0, stream>>>(kw, qw, kwA, qwA);

    dim3 cgrid(48, 2, 8);
    conv_mfma<false, false><<<cgrid, 512, 0, stream>>>(xpad1, kwA, kcS);
    conv_mfma<false, false><<<cgrid, 512, 0, stream>>>(xpad2, qwA, qcS);

    attn_mfma<<<dim3(4, 9, 8), 256, 0, stream>>>(kcS, qcS, attnT, part);
    finalize_k<<<1, 256, 0, stream>>>(part, momp, scal);

    norm_w<<<2592, 256, 0, stream>>>(attnT, scal, normW);
    conv_mfma<true, true><<<cgrid, 512, 0, stream>>>(xpad1, normW, (float*)d_out);
}

// Round 6
// 284.546 us; speedup vs baseline: 16.1253x; 1.6547x over previous
//
#include <hip/hip_runtime.h>
#include <math.h>

typedef __attribute__((ext_vector_type(8))) short s16x8;
typedef __attribute__((ext_vector_type(4))) short s16x4;
typedef __attribute__((ext_vector_type(4))) float f32x4;

typedef unsigned int u32;
typedef __attribute__((address_space(3))) u32* lds_u32p;
typedef const __attribute__((address_space(1))) u32* glb_u32p;

namespace {

constexpr int B  = 8;
constexpr int C  = 192;
constexpr int H  = 96;
constexpr int W  = 96;
constexpr int FK = 9;
constexpr int HP = 98;    // padded
constexpr int L  = 1024;  // 32x32 patch grid per phase
constexpr int WCHUNK = FK * 12 * 6;          // 648 packed 1KB chunks per tensor
constexpr int WELEM  = WCHUNK * 512;         // 331776 bf16 elements

__device__ inline unsigned short f2b(float f) {
    unsigned int x = __float_as_uint(f);
    x += 0x7fffu + ((x >> 16) & 1u);
    return (unsigned short)(x >> 16);
}

// ---------------------------------------------------------------------------
// x[b][c][96][96] f32 -> xpadT[b][98][98][192] bf16 (borders pre-zeroed)
// ---------------------------------------------------------------------------
__global__ __launch_bounds__(256) void prep_x(const float* __restrict__ x,
                                              unsigned short* __restrict__ xpadT) {
    __shared__ float xs[192][33];
    const int tid = threadIdx.x;
    const int x0  = blockIdx.x * 32;
    const int y   = blockIdx.y;
    const int b   = blockIdx.z;
    for (int e = tid; e < 192 * 32; e += 256) {
        const int ci = e >> 5, xx = e & 31;
        xs[ci][xx] = x[(((size_t)b * C + ci) * H + y) * W + x0 + xx];
    }
    __syncthreads();
    for (int e = tid; e < 32 * 192; e += 256) {
        const int pos = e / 192, ci = e - pos * 192;
        xpadT[(((size_t)(b * HP + y + 1)) * HP + x0 + pos + 1) * 192 + ci] = f2b(xs[ci][pos]);
    }
}

// ---------------------------------------------------------------------------
// pack weights into fragment-linear layout:
//   dst[(((p*12 + cot)*6 + cc))*512 + lane*8 + t]  = w[co][ci][p]
//   lane = kg*16 + r15; co = cot*16 + r15; ci = cc*32 + kg*8 + t
// ---------------------------------------------------------------------------
__global__ __launch_bounds__(256) void prep_w(const float* __restrict__ kw,
                                              const float* __restrict__ qw,
                                              unsigned short* __restrict__ kwA,
                                              unsigned short* __restrict__ qwA) {
    int idx = blockIdx.x * 256 + threadIdx.x;
    const float* src = kw;
    unsigned short* dst = kwA;
    if (idx >= WELEM) { idx -= WELEM; src = qw; dst = qwA; }
    const int chunk = idx >> 9, within = idx & 511;
    const int lane = within >> 3, t = within & 7;
    const int kg = lane >> 4, r15 = lane & 15;
    const int cc = chunk % 6, c2 = chunk / 6;
    const int cot = c2 % 12, p = c2 / 12;
    const int co = cot * 16 + r15;
    const int ci = cc * 32 + kg * 8 + t;
    dst[idx] = f2b(src[((size_t)co * C + ci) * FK + p]);
}

// ---------------------------------------------------------------------------
// MFMA implicit-GEMM conv3x3, SMALL blocks for TLP.
// Block: 256 thr = 4 waves; wave wc covers co strip wc*48, full 48 s, 1 y.
// Tile = 192 co x 48 s x 1 y. LDS = one 50-pos x 192ci window (19.2 KB),
// staged per dy via global_load_lds with pre-swizzled global source.
// Packed A frags (coalesced 1KB/wave) straight from global (L2-hot).
// grid (96 y, 2 sx, 8 b) = 1536 blocks (~6/CU, ~3 resident).
// ---------------------------------------------------------------------------
template <bool OUTF32, bool PERB>
__global__ __launch_bounds__(256, 3)
void conv_mfma(const unsigned short* __restrict__ xpadT,
               const unsigned short* __restrict__ wA,
               void* __restrict__ yout) {
    __shared__ __align__(16) char smem[50 * 384];   // 19200 B
    const int tid  = threadIdx.x;
    const int y    = blockIdx.x;
    const int sx   = blockIdx.y;        // s half (48 outputs)
    const int b    = blockIdx.z;
    const int lane = tid & 63, wc = tid >> 6;   // wave = co strip wc*48
    const int ln15 = lane & 15, kg = lane >> 4;

    const unsigned short* wp = PERB ? (wA + (size_t)b * WELEM) : wA;

    // staging: 50 pos x 24 chunks(16B) = 1200 chunks; 4 rounds + 176 tail
    int gfull[4];
#pragma unroll
    for (int it = 0; it < 4; ++it) {
        const int m = it * 256 + tid;
        const int q = m / 24, c16 = m - q * 24;
        gfull[it] = (sx * 48 + q) * 384 + ((c16 * 16) ^ ((q & 7) << 4));
    }
    int gtail = 0;
    if (tid < 176) {
        const int m = 1024 + tid;
        const int q = m / 24, c16 = m - q * 24;
        gtail = (sx * 48 + q) * 384 + ((c16 * 16) ^ ((q & 7) << 4));
    }

    auto stage = [&](int prow) {
        const char* rowbase = (const char*)(xpadT + ((size_t)(b * HP + prow)) * HP * 192);
#pragma unroll
        for (int it = 0; it < 4; ++it)
            __builtin_amdgcn_global_load_lds(
                (glb_u32p)(const void*)(rowbase + gfull[it]),
                (lds_u32p)(void*)(smem + it * 4096 + wc * 1024), 16, 0, 0);
        if (tid < 176)
            __builtin_amdgcn_global_load_lds(
                (glb_u32p)(const void*)(rowbase + gtail),
                (lds_u32p)(void*)(smem + 16384 + wc * 1024), 16, 0, 0);
    };

    f32x4 acc[3][3];
#pragma unroll
    for (int i = 0; i < 3; ++i)
#pragma unroll
        for (int j = 0; j < 3; ++j)
            acc[i][j] = (f32x4){0.f, 0.f, 0.f, 0.f};

    for (int dy = 0; dy < 3; ++dy) {
        if (dy) __syncthreads();         // prior compute done with LDS
        stage(y + dy);
        asm volatile("s_waitcnt vmcnt(0)" ::: "memory");
        __syncthreads();

        for (int cc = 0; cc < 6; ++cc) {
            s16x8 af[3][3];
#pragma unroll
            for (int dx = 0; dx < 3; ++dx)
#pragma unroll
                for (int i = 0; i < 3; ++i) {
                    const int chunkid = ((3 * dy + dx) * 12 + wc * 3 + i) * 6 + cc;
                    af[dx][i] = *(const s16x8*)(wp + (size_t)chunkid * 512 + lane * 8);
                }
            s16x8 bv[3][3];
#pragma unroll
            for (int j = 0; j < 3; ++j)
#pragma unroll
                for (int dx = 0; dx < 3; ++dx) {
                    const int q = j * 16 + ln15 + dx;
                    bv[j][dx] = *(const s16x8*)(smem + q * 384 +
                                    ((cc * 64 + kg * 16) ^ ((q & 7) << 4)));
                }
#pragma unroll
            for (int i = 0; i < 3; ++i)
#pragma unroll
                for (int j = 0; j < 3; ++j)
#pragma unroll
                    for (int dx = 0; dx < 3; ++dx)
                        acc[i][j] = __builtin_amdgcn_mfma_f32_16x16x32_bf16(
                            af[dx][i], bv[j][dx], acc[i][j], 0, 0, 0);
        }
    }

    if (!OUTF32) {
        // phase layout: dst[((b*9 + (y%3)*3 + s%3)*192 + co)*1024 + (y/3)*32 + s/3]
        unsigned short* yb = (unsigned short*)yout;
        const int ph = y % 3, lh = y / 3;
        int poff[3];
#pragma unroll
        for (int j = 0; j < 3; ++j) {
            const int s  = sx * 48 + j * 16 + ln15;
            const int pw = s % 3, lw = s / 3;
            poff[j] = ((b * FK + ph * 3 + pw) * C) * L + lh * 32 + lw;
        }
#pragma unroll
        for (int i = 0; i < 3; ++i)
#pragma unroll
            for (int rr = 0; rr < 4; ++rr) {
                const int co = wc * 48 + i * 16 + kg * 4 + rr;
#pragma unroll
                for (int j = 0; j < 3; ++j)
                    yb[(size_t)poff[j] + co * L] = f2b(acc[i][j][rr]);
            }
    } else {
        float* yf = (float*)yout;
#pragma unroll
        for (int i = 0; i < 3; ++i)
#pragma unroll
            for (int rr = 0; rr < 4; ++rr) {
                const int co = wc * 48 + i * 16 + kg * 4 + rr;
                const size_t base = (((size_t)b * C + co) * H + y) * W;
#pragma unroll
                for (int j = 0; j < 3; ++j)
                    yf[base + sx * 48 + j * 16 + ln15] = acc[i][j][rr];
            }
    }
}

// ---------------------------------------------------------------------------
// attn MFMA: per (b,phase) GEMM D[c][o] = sum_k Kc[c][k]*Qc[o][k], K=1024.
// Block = 96c x 96o quarter, 4 waves 48x48. BK=64 double-buffered staging.
// Epilogue: attnT[b][p][o][c] f32 + fused f64 sum/ssq partials.
// grid (4, 9, 8), 256 thr
// ---------------------------------------------------------------------------
__global__ __launch_bounds__(256, 3)
void attn_mfma(const unsigned short* __restrict__ kcS,
               const unsigned short* __restrict__ qcS,
               float* __restrict__ attnT,
               double* __restrict__ part) {
    __shared__ __align__(16) char smem[2][24576];   // [buf][A 12KB | B 12KB]
    const int tid  = threadIdx.x;
    const int lane = tid & 63, wid = tid >> 6;
    const int wq   = wid & 1, wp = wid >> 1;
    const int ln15 = lane & 15, kg = lane >> 4;
    const int of   = blockIdx.x & 1, cf = blockIdx.x >> 1;
    const int p    = blockIdx.y, b = blockIdx.z;

    const char* Abase = (const char*)(kcS + ((size_t)(b * FK + p) * C + cf * 96) * L);
    const char* Bbase = (const char*)(qcS + ((size_t)(b * FK + p) * C + of * 96) * L);

    int gofs[3];
#pragma unroll
    for (int it = 0; it < 3; ++it) {
        const int chunk = it * 256 + tid;
        const int row = chunk >> 3, c16 = chunk & 7;
        gofs[it] = row * 2048 + ((c16 * 16) ^ ((row & 7) << 4));
    }

    auto stage = [&](int bufi, int t) {
        const char* Ab = Abase + t * 128;
        const char* Bb = Bbase + t * 128;
        char* lb = (char*)smem[bufi];
#pragma unroll
        for (int it = 0; it < 3; ++it)
            __builtin_amdgcn_global_load_lds(
                (glb_u32p)(const void*)(Ab + gofs[it]),
                (lds_u32p)(void*)(lb + it * 4096 + wid * 1024), 16, 0, 0);
#pragma unroll
        for (int it = 0; it < 3; ++it)
            __builtin_amdgcn_global_load_lds(
                (glb_u32p)(const void*)(Bb + gofs[it]),
                (lds_u32p)(void*)(lb + 12288 + it * 4096 + wid * 1024), 16, 0, 0);
    };

    f32x4 acc[3][3];
#pragma unroll
    for (int i = 0; i < 3; ++i)
#pragma unroll
        for (int j = 0; j < 3; ++j)
            acc[i][j] = (f32x4){0.f, 0.f, 0.f, 0.f};

    stage(0, 0);
    asm volatile("s_waitcnt vmcnt(0)" ::: "memory");
    __syncthreads();

    for (int t = 0; t < 16; ++t) {
        if (t < 15) stage((t + 1) & 1, t + 1);
        const char* lb = (const char*)smem[t & 1];
#pragma unroll
        for (int ks = 0; ks < 2; ++ks) {
            s16x8 af[3], bf[3];
#pragma unroll
            for (int i = 0; i < 3; ++i) {
                const int row = wp * 48 + i * 16 + ln15;
                af[i] = *(const s16x8*)(lb + row * 128 +
                                        ((ks * 64 + kg * 16) ^ ((row & 7) << 4)));
            }
#pragma unroll
            for (int j = 0; j < 3; ++j) {
                const int row = wq * 48 + j * 16 + ln15;
                bf[j] = *(const s16x8*)(lb + 12288 + row * 128 +
                                        ((ks * 64 + kg * 16) ^ ((row & 7) << 4)));
            }
#pragma unroll
            for (int i = 0; i < 3; ++i)
#pragma unroll
                for (int j = 0; j < 3; ++j)
                    acc[i][j] = __builtin_amdgcn_mfma_f32_16x16x32_bf16(
                        af[i], bf[j], acc[i][j], 0, 0, 0);
        }
        if (t < 15) {
            asm volatile("s_waitcnt vmcnt(0)" ::: "memory");
            __syncthreads();
        }
    }

    __syncthreads();
    double s = 0.0, ss = 0.0;
#pragma unroll
    for (int i = 0; i < 3; ++i)
#pragma unroll
        for (int j = 0; j < 3; ++j)
#pragma unroll
            for (int r = 0; r < 4; ++r) {
                const double v = (double)acc[i][j][r];
                s += v; ss += v * v;
            }
    double* ls  = (double*)&smem[0][0];
    double* lss = ls + 256;
    ls[tid] = s; lss[tid] = ss;
    __syncthreads();
    for (int st = 128; st; st >>= 1) {
        if (tid < st) { ls[tid] += ls[tid + st]; lss[tid] += lss[tid + st]; }
        __syncthreads();
    }
    if (tid == 0) {
        const int bf_ = ((b * FK + p) << 2) + blockIdx.x;
        part[2 * bf_]     = ls[0];
        part[2 * bf_ + 1] = lss[0];
    }

    float* ap = attnT + (size_t)(b * FK + p) * C * C;
#pragma unroll
    for (int i = 0; i < 3; ++i) {
        const int c0 = cf * 96 + wp * 48 + i * 16 + kg * 4;
#pragma unroll
        for (int j = 0; j < 3; ++j) {
            const int o = of * 96 + wq * 48 + j * 16 + ln15;
            *(f32x4*)(ap + o * C + c0) = acc[i][j];
        }
    }
}

__global__ __launch_bounds__(256) void finalize_k(const double* __restrict__ part,
                                                  const float* __restrict__ momp,
                                                  float* __restrict__ scal) {
    __shared__ double ls[256], lss[256];
    double s = 0.0, ss = 0.0;
    for (int i = threadIdx.x; i < 288; i += 256) {
        s += part[2 * i]; ss += part[2 * i + 1];
    }
    ls[threadIdx.x] = s; lss[threadIdx.x] = ss;
    __syncthreads();
    for (int st = 128; st; st >>= 1) {
        if (threadIdx.x < st) {
            ls[threadIdx.x]  += ls[threadIdx.x + st];
            lss[threadIdx.x] += lss[threadIdx.x + st];
        }
        __syncthreads();
    }
    if (threadIdx.x == 0) {
        const double n    = (double)(B * FK * C * C);
        const double mean = ls[0] / n;
        double var        = (lss[0] - ls[0] * ls[0] / n) / (n - 1.0);
        if (var < 0.0) var = 0.0;
        const double scale = 1.0 / (sqrt(var) + 1e-4);
        scal[0] = (float)((double)momp[0] + scale);  // alpha
        scal[1] = (float)(-mean * scale);            // beta
    }
}

// ---------------------------------------------------------------------------
// normW packed: out[b][chunk][lane][t] = bf16(alpha*attnT[b][p][co][ci]+beta)
// chunk = (p*12 + cot)*6 + cc; co = cot*16 + (lane&15); ci = cc*32+(lane>>4)*8+t
// ---------------------------------------------------------------------------
__global__ __launch_bounds__(256) void norm_w(const float* __restrict__ attnT,
                                              const float* __restrict__ scal,
                                              unsigned short* __restrict__ o) {
    const float alpha = scal[0], beta = scal[1];
    const int g = (blockIdx.x * 256 + threadIdx.x) * 4;
    const int chunk = g >> 9, within = g & 511;
    const int lane = within >> 3, t0 = within & 7;
    const int cc = chunk % 6, c2 = chunk / 6;
    const int cot = c2 % 12, pb = c2 / 12;
    const int p = pb % FK, b = pb / FK;
    const int co = cot * 16 + (lane & 15);
    const int ci = cc * 32 + (lane >> 4) * 8 + t0;
    const float4 v = *(const float4*)(attnT + (((size_t)(b * FK + p) * C + co) * C + ci));
    s16x4 r;
    r[0] = (short)f2b(fmaf(alpha, v.x, beta));
    r[1] = (short)f2b(fmaf(alpha, v.y, beta));
    r[2] = (short)f2b(fmaf(alpha, v.z, beta));
    r[3] = (short)f2b(fmaf(alpha, v.w, beta));
    *(s16x4*)(o + g) = r;
}

} // anonymous namespace

extern "C" void kernel_launch(void* const* d_in, const int* in_sizes, int n_in,
                              void* d_out, int out_size, void* d_ws, size_t ws_size,
                              hipStream_t stream) {
    (void)in_sizes; (void)n_in; (void)out_size; (void)ws_size;
    const float* x1   = (const float*)d_in[0];
    const float* x2   = (const float*)d_in[1];
    const float* kw   = (const float*)d_in[2];
    const float* qw   = (const float*)d_in[3];
    const float* momp = (const float*)d_in[4];

    char* ws = (char*)d_ws;
    unsigned short* xpad1 = (unsigned short*)ws;                   // 29,503,488
    unsigned short* xpad2 = (unsigned short*)(ws + 29503488);      // 29,503,488
    unsigned short* kwA   = (unsigned short*)(ws + 59006976);      //    663,552
    unsigned short* qwA   = (unsigned short*)(ws + 59670528);      //    663,552
    unsigned short* kcS   = (unsigned short*)(ws + 60334080);      // 28,311,552
    float*          attnT = (float*)(ws + 88645632);               // 10,616,832
    double*         part  = (double*)(ws + 99262464);              //      4,608
    float*          scal  = (float*)(ws + 99278848);               //          8
    unsigned short* normW = kcS;            // kcS dead after attn; 5,308,416 B
    unsigned short* qcS   = (unsigned short*)d_out;  // scratch until final conv

    hipMemsetAsync(xpad1, 0, 2 * 29503488ULL, stream);

    dim3 pgrid(3, 96, 8);
    prep_x<<<pgrid, 256, 0, stream>>>(x1, xpad1);
    prep_x<<<pgrid, 256, 0, stream>>>(x2, xpad2);
    prep_w<<<2592, 256, 0, stream>>>(kw, qw, kwA, qwA);

    dim3 cgrid(96, 2, 8);
    conv_mfma<false, false><<<cgrid, 256, 0, stream>>>(xpad1, kwA, kcS);
    conv_mfma<false, false><<<cgrid, 256, 0, stream>>>(xpad2, qwA, qcS);

    attn_mfma<<<dim3(4, 9, 8), 256, 0, stream>>>(kcS, qcS, attnT, part);
    finalize_k<<<1, 256, 0, stream>>>(part, momp, scal);

    norm_w<<<2592, 256, 0, stream>>>(attnT, scal, normW);
    conv_mfma<true, true><<<cgrid, 256, 0, stream>>>(xpad1, normW, (float*)d_out);
}